// Round 3
// baseline (5030.944 us; speedup 1.0000x reference)
//
#include <hip/hip_runtime.h>

// Problem constants: N=16, C_IN=32, C_OUT=64, H=W=128, D=5, K=800
#define R_SZ  (16*32*32*81)      // 1,327,104 floats
#define Q_SZ  (16*800*800)       // 10,240,000
#define P_SZ  (16*800*64)        // 819,200
#define LI_SZ (16*10*80*80)      // 1,024,000

typedef unsigned short u16;
typedef __attribute__((ext_vector_type(8))) short bf16x8;
typedef __attribute__((ext_vector_type(4))) float f32x4;

#define MFMA16(a, b, c) __builtin_amdgcn_mfma_f32_16x16x32_bf16(a, b, c, 0, 0, 0)

__device__ __forceinline__ float alpha_scale(const float* alpha, const float* reg, int n) {
  return alpha[n] * (16384.0f * reg[0] / 800.0f);
}

__device__ __forceinline__ u16 f2bf(float f) {
  union { float f; unsigned u; } v; v.f = f;
  unsigned r = v.u + 0x7FFFu + ((v.u >> 16) & 1u);
  return (u16)(r >> 16);
}
__device__ __forceinline__ float bf2f(u16 h) {
  union { unsigned u; float f; } v; v.u = ((unsigned)h) << 16; return v.f;
}

__device__ __forceinline__ bf16x8 load8(const u16* p) {
  union { uint2 d[2]; bf16x8 v; } u;
  u.d[0] = *(const uint2*)p;
  u.d[1] = *(const uint2*)(p + 4);
  return u.v;
}

// Build a shifted fragment from a 16-element window held in 8 dwords.
__device__ __forceinline__ bf16x8 build_frag(const unsigned* w, int s) {
  union { unsigned u[4]; bf16x8 v; } f;
  int b = s >> 1;
  if (s & 1) {
    #pragma unroll
    for (int k = 0; k < 4; ++k) f.u[k] = (w[b + k] >> 16) | (w[b + k + 1] << 16);
  } else {
    #pragma unroll
    for (int k = 0; k < 4; ++k) f.u[k] = w[b + k];
  }
  return f.v;
}

// Stage one image row (C channels, 128 px) into an LDS slot, hi/lo split.
__device__ __forceinline__ void stage_row(u16* slot, int partStride,
                                          const float* __restrict__ img,
                                          int C, int r, bool valid,
                                          int tid, int nthr) {
  for (int idx = tid; idx < C * 16; idx += nthr) {
    int c = idx >> 4, m = idx & 15;
    float v[8];
    if (valid) {
      const float* p = img + ((size_t)c * 128 + r) * 128 + m * 8;
      float4 a = *(const float4*)p;
      float4 b = *(const float4*)(p + 4);
      v[0]=a.x; v[1]=a.y; v[2]=a.z; v[3]=a.w; v[4]=b.x; v[5]=b.y; v[6]=b.z; v[7]=b.w;
    } else {
      #pragma unroll
      for (int k = 0; k < 8; ++k) v[k] = 0.0f;
    }
    union { u16 s[8]; uint2 d[2]; } hh, ll;
    #pragma unroll
    for (int k = 0; k < 8; ++k) {
      u16 h = f2bf(v[k]);
      hh.s[k] = h;
      ll.s[k] = f2bf(v[k] - bf2f(h));
    }
    u16* dh = slot + c * 136 + 4 + m * 8;
    *(uint2*)(dh)     = hh.d[0];
    *(uint2*)(dh + 4) = hh.d[1];
    u16* dl = dh + partStride;
    *(uint2*)(dl)     = ll.d[0];
    *(uint2*)(dl + 4) = ll.d[1];
  }
}

// -------------------- init: R = 0, P = a * d^T --------------------
__global__ void k_init(float* __restrict__ R, float* __restrict__ P,
                       const float* __restrict__ d, const float* __restrict__ alpha,
                       const float* __restrict__ reg) {
  int idx = blockIdx.x * 256 + threadIdx.x;
  if (idx < R_SZ) R[idx] = 0.0f;
  int e = idx - R_SZ;
  if (e >= 0 && e < P_SZ) {
    int n = e / 51200; int q = e % 51200;
    int co = q / 800;  int k = q % 800;
    float a = alpha_scale(alpha, reg, n);
    P[(n*800 + k)*64 + co] = a * d[(n*64 + co)*800 + k];
  }
}

// ---------------- R[n,c1,c2,u,v] = sum_ij x[c1,i,j]*x[c2,i+u-4,j+v-4] -------
// MFMA bf16 hi/lo split. grid = 16(n)*16(chunk of 8 rows); block = 9 waves
// (wave = du). dv processed in 3 groups of 3 to keep live accs at 48 VGPRs.
#define SLOT_US 8704     // ushorts per slot: 2 parts * 32 ch * 136
#define PSTR_32 4352

__global__ __launch_bounds__(576) void k_corrR_mfma(const float* __restrict__ x,
                                                    float* __restrict__ R) {
  __shared__ __align__(16) u16 lds[9 * SLOT_US];   // 156,672 B
  int n  = blockIdx.x >> 4;
  int r0 = (blockIdx.x & 15) << 3;
  int tid = threadIdx.x;
  const float* xn = x + (size_t)n * 32 * 128 * 128;

  // zero halo els [0,4) and [132,136): 9 slots * 2 parts * 32 ch = 576 items
  {
    int s = tid / 64, p = (tid >> 5) & 1, c = tid & 31;
    u16* b = lds + s * SLOT_US + p * PSTR_32 + c * 136;
    uint2 z; z.x = 0; z.y = 0;
    *(uint2*)b = z;
    *(uint2*)(b + 132) = z;
  }

  int wave = tid >> 6;          // 0..8
  int lane = tid & 63;
  int du = wave - 4;
  int lm = lane & 15, q = lane >> 4;
  float* Rn = R + (size_t)n * 32 * 32 * 81;
  int u = du + 4;

  for (int g = 0; g < 3; ++g) {
    __syncthreads();   // previous group done reading LDS
    // (re)build initial window: rows r0-4 .. r0+4
    for (int rr = -4; rr <= 4; ++rr) {
      int r = r0 + rr;
      stage_row(lds + ((r + 18) % 9) * SLOT_US, PSTR_32, xn, 32, r,
                (r >= 0 && r < 128), tid, 576);
    }

    f32x4 acc[3][2][2];
    #pragma unroll
    for (int d = 0; d < 3; ++d)
      #pragma unroll
      for (int mt = 0; mt < 2; ++mt)
        #pragma unroll
        for (int nt = 0; nt < 2; ++nt)
          acc[d][mt][nt] = (f32x4){0.f, 0.f, 0.f, 0.f};

    for (int i = r0; i < r0 + 8; ++i) {
      __syncthreads();
      const u16* A  = lds + ((i + 18) % 9) * SLOT_US;
      const u16* Bp = lds + ((i + du + 18) % 9) * SLOT_US;
      #pragma unroll
      for (int ks = 0; ks < 4; ++ks) {
        int kb = ks * 32 + q * 8;
        bf16x8 af[2][2];
        #pragma unroll
        for (int pa = 0; pa < 2; ++pa)
          #pragma unroll
          for (int mt = 0; mt < 2; ++mt)
            af[pa][mt] = load8(A + pa * PSTR_32 + (mt * 16 + lm) * 136 + 4 + kb);
        #pragma unroll
        for (int nt = 0; nt < 2; ++nt)
          #pragma unroll
          for (int pb = 0; pb < 2; ++pb) {
            const u16* wp = Bp + pb * PSTR_32 + (nt * 16 + lm) * 136 + kb;
            uint4 w0 = *(const uint4*)wp;
            uint4 w1 = *(const uint4*)(wp + 8);
            unsigned w[8] = {w0.x, w0.y, w0.z, w0.w, w1.x, w1.y, w1.z, w1.w};
            #pragma unroll
            for (int d = 0; d < 3; ++d) {
              bf16x8 bf = build_frag(w, g * 3 + d);
              #pragma unroll
              for (int mt = 0; mt < 2; ++mt)
                #pragma unroll
                for (int pa = 0; pa < 2; ++pa) {
                  if (pa == 1 && pb == 1) continue;   // skip lo*lo
                  acc[d][mt][nt] = MFMA16(af[pa][mt], bf, acc[d][mt][nt]);
                }
            }
          }
      }
      __syncthreads();
      if (i + 1 < r0 + 8) {
        int r = i + 5;
        stage_row(lds + ((r + 18) % 9) * SLOT_US, PSTR_32, xn, 32, r,
                  (r >= 0 && r < 128), tid, 576);
      }
    }

    #pragma unroll
    for (int d = 0; d < 3; ++d)
      #pragma unroll
      for (int mt = 0; mt < 2; ++mt)
        #pragma unroll
        for (int nt = 0; nt < 2; ++nt)
          #pragma unroll
          for (int r = 0; r < 4; ++r) {
            int c1 = mt * 16 + q * 4 + r;
            int c2 = nt * 16 + lm;
            atomicAdd(&Rn[(c1 * 32 + c2) * 81 + u * 9 + g * 3 + d],
                      acc[d][mt][nt][r]);
          }
  }
}

// ------- P[n,(ci,a,e),co] += sum_ij y[co,i,j]*x[ci,i+a-2,j+e-2]  (MFMA) -----
// grid = 16(n)*16(chunk). Block = 10 waves: wave = (du+2)*2 + mhalf.
// dv (5) processed in groups of 3 + 2.
#define YPSTR 8704   // 64 ch * 136

__global__ __launch_bounds__(640) void k_corrP_mfma(const float* __restrict__ x,
                                                    const float* __restrict__ y,
                                                    float* __restrict__ P) {
  __shared__ __align__(16) u16 xs[5 * SLOT_US];   // 87,040 B
  __shared__ __align__(16) u16 ys[2 * YPSTR];     // 34,816 B
  int n  = blockIdx.x >> 4;
  int r0 = (blockIdx.x & 15) << 3;
  int tid = threadIdx.x;
  const float* xn = x + (size_t)n * 32 * 128 * 128;
  const float* yn = y + (size_t)n * 64 * 128 * 128;

  if (tid < 320) {
    int s = tid / 64, p = (tid >> 5) & 1, c = tid & 31;
    u16* b = xs + s * SLOT_US + p * PSTR_32 + c * 136;
    uint2 z; z.x = 0; z.y = 0;
    *(uint2*)b = z;
    *(uint2*)(b + 132) = z;
  }

  int wave = tid >> 6;            // 0..9
  int lane = tid & 63;
  int du = (wave >> 1) - 2;
  int mh = wave & 1;
  int lm = lane & 15, q = lane >> 4;
  float* Pn = P + (size_t)n * 800 * 64;
  int a = du + 2;

  for (int g = 0; g < 2; ++g) {
    int nd = (g == 0) ? 3 : 2;
    __syncthreads();
    for (int rr = -2; rr <= 2; ++rr) {
      int r = r0 + rr;
      stage_row(xs + ((r + 10) % 5) * SLOT_US, PSTR_32, xn, 32, r,
                (r >= 0 && r < 128), tid, 640);
    }
    stage_row(ys, YPSTR, yn, 64, r0, true, tid, 640);

    f32x4 acc[3][2][2];
    #pragma unroll
    for (int d = 0; d < 3; ++d)
      #pragma unroll
      for (int mt = 0; mt < 2; ++mt)
        #pragma unroll
        for (int nt = 0; nt < 2; ++nt)
          acc[d][mt][nt] = (f32x4){0.f, 0.f, 0.f, 0.f};

    for (int i = r0; i < r0 + 8; ++i) {
      __syncthreads();
      const u16* Bp = xs + ((i + du + 10) % 5) * SLOT_US;
      #pragma unroll
      for (int ks = 0; ks < 4; ++ks) {
        int kb = ks * 32 + q * 8;
        bf16x8 af[2][2];
        #pragma unroll
        for (int pa = 0; pa < 2; ++pa)
          #pragma unroll
          for (int mt = 0; mt < 2; ++mt)
            af[pa][mt] = load8(ys + pa * YPSTR + (mh * 32 + mt * 16 + lm) * 136 + 4 + kb);
        #pragma unroll
        for (int nt = 0; nt < 2; ++nt)
          #pragma unroll
          for (int pb = 0; pb < 2; ++pb) {
            const u16* wp = Bp + pb * PSTR_32 + (nt * 16 + lm) * 136 + kb;
            uint4 w0 = *(const uint4*)wp;
            uint4 w1 = *(const uint4*)(wp + 8);
            unsigned w[8] = {w0.x, w0.y, w0.z, w0.w, w1.x, w1.y, w1.z, w1.w};
            #pragma unroll
            for (int d = 0; d < 3; ++d) {
              if (d >= nd) continue;
              bf16x8 bf = build_frag(w, g * 3 + d + 2);
              #pragma unroll
              for (int mt = 0; mt < 2; ++mt)
                #pragma unroll
                for (int pa = 0; pa < 2; ++pa) {
                  if (pa == 1 && pb == 1) continue;
                  acc[d][mt][nt] = MFMA16(af[pa][mt], bf, acc[d][mt][nt]);
                }
            }
          }
      }
      __syncthreads();
      if (i + 1 < r0 + 8) {
        int r = i + 3;
        stage_row(xs + ((r + 10) % 5) * SLOT_US, PSTR_32, xn, 32, r,
                  (r >= 0 && r < 128), tid, 640);
        stage_row(ys, YPSTR, yn, 64, i + 1, true, tid, 640);
      }
    }

    #pragma unroll
    for (int d = 0; d < 3; ++d) {
      if (d >= nd) continue;
      #pragma unroll
      for (int mt = 0; mt < 2; ++mt)
        #pragma unroll
        for (int nt = 0; nt < 2; ++nt)
          #pragma unroll
          for (int r = 0; r < 4; ++r) {
            int co = mh * 32 + mt * 16 + q * 4 + r;
            int ci = nt * 16 + lm;
            atomicAdd(&Pn[(ci * 25 + a * 5 + g * 3 + d) * 64 + co],
                      acc[d][mt][nt][r]);
          }
    }
  }
}

// -------------------- Q[n,k1,k2] = R[n,c1,c2,b-a+4,f-e+4] (+ a on diag) ----
__global__ void k_buildQ(const float* __restrict__ R, float* __restrict__ Q,
                         const float* __restrict__ alpha, const float* __restrict__ reg) {
  int bid = blockIdx.x;
  int n = bid / 800, k1 = bid % 800;
  int c1 = k1 / 25, r1 = k1 % 25, a = r1 / 5, e = r1 % 5;
  float av = alpha_scale(alpha, reg, n);
  const float* Rn = R + ((size_t)n*32 + c1) * 32 * 81;
  float* Qrow = Q + ((size_t)n*800 + k1) * 800;
  for (int k2 = threadIdx.x; k2 < 800; k2 += 256) {
    int c2 = k2 / 25, r2 = k2 % 25, b = r2 / 5, f = r2 % 5;
    float v = Rn[c2*81 + (b - a + 4)*9 + (f - e + 4)];
    if (k2 == k1) v += av;
    Qrow[k2] = v;
  }
}

// -------------------- Cholesky: diag factor + explicit inverse --------------
__global__ __launch_bounds__(256) void k_chol_diag(float* __restrict__ Q,
                                                   float* __restrict__ Linv, int t) {
  int n = blockIdx.x;
  int tid = threadIdx.x;
  __shared__ float A[80*81];
  __shared__ float B[80*81];
  float* Qn = Q + (size_t)n * 640000;
  int base = t * 80;
  for (int idx = tid; idx < 6400; idx += 256) {
    int r = idx / 80, c = idx % 80;
    A[r*81 + c] = Qn[(base + r)*800 + base + c];
  }
  __syncthreads();
  for (int j = 0; j < 80; ++j) {
    if (tid == 0) A[j*81 + j] = sqrtf(A[j*81 + j]);
    __syncthreads();
    float dinv = 1.0f / A[j*81 + j];
    for (int i = j + 1 + tid; i < 80; i += 256) A[i*81 + j] *= dinv;
    __syncthreads();
    int m = 79 - j;
    for (int idx = tid; idx < m*m; idx += 256) {
      int i = j + 1 + idx / m, k = j + 1 + idx % m;
      if (k <= i) A[i*81 + k] -= A[i*81 + j] * A[k*81 + j];
    }
    __syncthreads();
  }
  if (tid < 80) {
    int j = tid;
    B[j*81 + j] = 1.0f / A[j*81 + j];
    for (int i = j + 1; i < 80; ++i) {
      float s = 0.0f;
      for (int k = j; k < i; ++k) s += A[i*81 + k] * B[k*81 + j];
      B[i*81 + j] = -s / A[i*81 + i];
    }
  }
  __syncthreads();
  float* Ln = Linv + ((size_t)n*10 + t) * 6400;
  for (int idx = tid; idx < 6400; idx += 256) {
    int r = idx / 80, c = idx % 80;
    Ln[idx] = (r >= c) ? B[r*81 + c] : 0.0f;
  }
}

// panel: W = A_panel * Linv^T  (overwrites panel with L)
__global__ __launch_bounds__(256) void k_chol_panel(float* __restrict__ Q,
                                                    const float* __restrict__ Linv,
                                                    int t, int nt) {
  int n = blockIdx.x / nt, it = blockIdx.x % nt;
  int R0 = 80*(t+1) + 80*it, C0 = 80*t;
  __shared__ float As[80*82];
  __shared__ float Bs[80*82];
  float* Qn = Q + (size_t)n * 640000;
  const float* Ln = Linv + ((size_t)n*10 + t) * 6400;
  int tid = threadIdx.x;
  for (int idx = tid; idx < 6400; idx += 256) {
    int r = idx / 80, c = idx % 80;
    As[r*82 + c] = Qn[(R0 + r)*800 + C0 + c];
    Bs[r*82 + c] = Ln[idx];
  }
  __syncthreads();
  int tc = tid & 15, tr = tid >> 4;
  float acc[5][5];
  #pragma unroll
  for (int a = 0; a < 5; ++a)
    #pragma unroll
    for (int b = 0; b < 5; ++b) acc[a][b] = 0.0f;
  for (int k = 0; k < 80; ++k) {
    float av[5], bv[5];
    #pragma unroll
    for (int d = 0; d < 5; ++d) { av[d] = As[(5*tr + d)*82 + k]; bv[d] = Bs[(5*tc + d)*82 + k]; }
    #pragma unroll
    for (int a = 0; a < 5; ++a)
      #pragma unroll
      for (int b = 0; b < 5; ++b) acc[a][b] += av[a] * bv[b];
  }
  #pragma unroll
  for (int a = 0; a < 5; ++a)
    #pragma unroll
    for (int b = 0; b < 5; ++b)
      Qn[(R0 + 5*tr + a)*800 + C0 + 5*tc + b] = acc[a][b];
}

// trailing: A_IJ -= W_I * W_J^T (lower tiles only)
__global__ __launch_bounds__(256) void k_chol_trail(float* __restrict__ Q, int t, int nt) {
  int ntile = nt * (nt + 1) / 2;
  int n = blockIdx.x / ntile;
  int rr = blockIdx.x % ntile;
  int i = 0;
  while (rr >= i + 1) { rr -= (i + 1); ++i; }
  int j = rr;
  int R0 = 80*(t+1+i), C0 = 80*(t+1+j), K0 = 80*t;
  __shared__ float Ws[80*82];
  __shared__ float Vs[80*82];
  float* Qn = Q + (size_t)n * 640000;
  int tid = threadIdx.x;
  for (int idx = tid; idx < 6400; idx += 256) {
    int r = idx / 80, c = idx % 80;
    Ws[r*82 + c] = Qn[(R0 + r)*800 + K0 + c];
    Vs[r*82 + c] = Qn[(C0 + r)*800 + K0 + c];
  }
  __syncthreads();
  int tc = tid & 15, tr = tid >> 4;
  float acc[5][5];
  #pragma unroll
  for (int a = 0; a < 5; ++a)
    #pragma unroll
    for (int b = 0; b < 5; ++b) acc[a][b] = 0.0f;
  for (int k = 0; k < 80; ++k) {
    float av[5], bv[5];
    #pragma unroll
    for (int d = 0; d < 5; ++d) { av[d] = Ws[(5*tr + d)*82 + k]; bv[d] = Vs[(5*tc + d)*82 + k]; }
    #pragma unroll
    for (int a = 0; a < 5; ++a)
      #pragma unroll
      for (int b = 0; b < 5; ++b) acc[a][b] += av[a] * bv[b];
  }
  #pragma unroll
  for (int a = 0; a < 5; ++a)
    #pragma unroll
    for (int b = 0; b < 5; ++b)
      Qn[(R0 + 5*tr + a)*800 + C0 + 5*tc + b] -= acc[a][b];
}

// -------------------- blocked triangular solves + output transpose ---------
__global__ __launch_bounds__(256) void k_solve(const float* __restrict__ Q,
                                               const float* __restrict__ Linv,
                                               const float* __restrict__ P,
                                               float* __restrict__ out) {
  int n = blockIdx.x >> 3;
  int g = blockIdx.x & 7;
  int tid = threadIdx.x;
  __shared__ float z[800*8];
  __shared__ float Lt[80*82];
  const float* Qn = Q + (size_t)n * 640000;

  for (int idx = tid; idx < 6400; idx += 256) {
    int k = idx >> 3, c = idx & 7;
    z[idx] = P[(n*800 + k)*64 + g*8 + c];
  }
  __syncthreads();

  for (int t = 0; t < 10; ++t) {
    for (int s = 0; s < t; ++s) {
      for (int idx = tid; idx < 6400; idx += 256)
        Lt[(idx/80)*82 + (idx%80)] = Qn[(80*t + idx/80)*800 + 80*s + idx%80];
      __syncthreads();
      for (int e = 0; e < 3; ++e) {
        int idx = tid + 256*e;
        if (idx < 640) {
          int c = idx & 7, r = idx >> 3;
          float acc = 0.0f;
          #pragma unroll 4
          for (int k = 0; k < 80; ++k) acc += Lt[r*82 + k] * z[(80*s + k)*8 + c];
          z[(80*t + r)*8 + c] -= acc;
        }
      }
      __syncthreads();
    }
    {
      const float* Ln = Linv + ((size_t)n*10 + t) * 6400;
      for (int idx = tid; idx < 6400; idx += 256)
        Lt[(idx/80)*82 + (idx%80)] = Ln[idx];
      __syncthreads();
      float tv[3];
      for (int e = 0; e < 3; ++e) {
        int idx = tid + 256*e;
        if (idx < 640) {
          int c = idx & 7, r = idx >> 3;
          float acc = 0.0f;
          #pragma unroll 4
          for (int k = 0; k < 80; ++k) acc += Lt[r*82 + k] * z[(80*t + k)*8 + c];
          tv[e] = acc;
        }
      }
      __syncthreads();
      for (int e = 0; e < 3; ++e) {
        int idx = tid + 256*e;
        if (idx < 640) { int c = idx & 7, r = idx >> 3; z[(80*t + r)*8 + c] = tv[e]; }
      }
      __syncthreads();
    }
  }

  for (int t = 9; t >= 0; --t) {
    for (int s = t + 1; s < 10; ++s) {
      for (int idx = tid; idx < 6400; idx += 256)
        Lt[(idx/80)*82 + (idx%80)] = Qn[(80*s + idx/80)*800 + 80*t + idx%80];
      __syncthreads();
      for (int e = 0; e < 3; ++e) {
        int idx = tid + 256*e;
        if (idx < 640) {
          int c = idx & 7, r = idx >> 3;
          float acc = 0.0f;
          #pragma unroll 4
          for (int k = 0; k < 80; ++k) acc += Lt[k*82 + r] * z[(80*s + k)*8 + c];
          z[(80*t + r)*8 + c] -= acc;
        }
      }
      __syncthreads();
    }
    {
      const float* Ln = Linv + ((size_t)n*10 + t) * 6400;
      for (int idx = tid; idx < 6400; idx += 256)
        Lt[(idx/80)*82 + (idx%80)] = Ln[idx];
      __syncthreads();
      float tv[3];
      for (int e = 0; e < 3; ++e) {
        int idx = tid + 256*e;
        if (idx < 640) {
          int c = idx & 7, r = idx >> 3;
          float acc = 0.0f;
          #pragma unroll 4
          for (int k = 0; k < 80; ++k) acc += Lt[k*82 + r] * z[(80*t + k)*8 + c];
          tv[e] = acc;
        }
      }
      __syncthreads();
      for (int e = 0; e < 3; ++e) {
        int idx = tid + 256*e;
        if (idx < 640) { int c = idx & 7, r = idx >> 3; z[(80*t + r)*8 + c] = tv[e]; }
      }
      __syncthreads();
    }
  }

  for (int idx = tid; idx < 6400; idx += 256) {
    int c = idx / 800, k = idx % 800;
    out[(size_t)(n*64 + g*8 + c)*800 + k] = z[k*8 + c];
  }
}

extern "C" void kernel_launch(void* const* d_in, const int* in_sizes, int n_in,
                              void* d_out, int out_size, void* d_ws, size_t ws_size,
                              hipStream_t stream) {
  const float* x     = (const float*)d_in[0];
  const float* d     = (const float*)d_in[1];
  const float* y     = (const float*)d_in[2];
  const float* alpha = (const float*)d_in[3];
  const float* reg   = (const float*)d_in[4];
  float* out = (float*)d_out;
  float* ws  = (float*)d_ws;

  float* R  = ws;
  float* Q  = ws + R_SZ;
  float* P  = ws + R_SZ + Q_SZ;
  float* Li = ws + R_SZ + Q_SZ + P_SZ;

  k_init<<<(R_SZ + P_SZ) / 256, 256, 0, stream>>>(R, P, d, alpha, reg);
  k_corrR_mfma<<<256, 576, 0, stream>>>(x, R);
  k_buildQ<<<16*800, 256, 0, stream>>>(R, Q, alpha, reg);
  k_corrP_mfma<<<256, 640, 0, stream>>>(x, y, P);

  for (int t = 0; t < 10; ++t) {
    k_chol_diag<<<16, 256, 0, stream>>>(Q, Li, t);
    int nt = 9 - t;
    if (nt > 0) {
      k_chol_panel<<<16*nt, 256, 0, stream>>>(Q, Li, t, nt);
      k_chol_trail<<<16*nt*(nt+1)/2, 256, 0, stream>>>(Q, t, nt);
    }
  }

  k_solve<<<128, 256, 0, stream>>>(Q, Li, P, out);
}

// Round 4
// 3170.729 us; speedup vs baseline: 1.5867x; 1.5867x over previous
//
#include <hip/hip_runtime.h>

// Problem constants: N=16, C_IN=32, C_OUT=64, H=W=128, D=5, K=800
#define R_SZ    737280           // 16 * 5(u) * 9(v) * 32 * 32
#define Q_SZ    10240000         // 16*800*800
#define P_SZ    819200           // 16*800*64
#define LI_SZ   1024000          // 16*10*80*80
#define PART_SZ 13107200         // max(Rpart 16*16*46080, Ppart 16*16*51200)

typedef unsigned short u16;
typedef __attribute__((ext_vector_type(8))) short bf16x8;
typedef __attribute__((ext_vector_type(4))) float f32x4;

#define MFMA16(a, b, c) __builtin_amdgcn_mfma_f32_16x16x32_bf16(a, b, c, 0, 0, 0)

__device__ __forceinline__ float alpha_scale(const float* alpha, const float* reg, int n) {
  return alpha[n] * (16384.0f * reg[0] / 800.0f);
}

__device__ __forceinline__ u16 f2bf(float f) {
  union { float f; unsigned u; } v; v.f = f;
  unsigned r = v.u + 0x7FFFu + ((v.u >> 16) & 1u);
  return (u16)(r >> 16);
}
__device__ __forceinline__ float bf2f(u16 h) {
  union { unsigned u; float f; } v; v.u = ((unsigned)h) << 16; return v.f;
}

__device__ __forceinline__ bf16x8 load8(const u16* p) {
  union { uint4 d; bf16x8 v; } u;
  u.d = *(const uint4*)p;
  return u.v;
}

// Build a shifted fragment from a 16-element window held in 8 dwords.
__device__ __forceinline__ bf16x8 build_frag(const unsigned* w, int s) {
  union { unsigned u[4]; bf16x8 v; } f;
  int b = s >> 1;
  if (s & 1) {
    #pragma unroll
    for (int k = 0; k < 4; ++k) f.u[k] = (w[b + k] >> 16) | (w[b + k + 1] << 16);
  } else {
    #pragma unroll
    for (int k = 0; k < 4; ++k) f.u[k] = w[b + k];
  }
  return f.v;
}

// Stage one image row (C channels, 128 px) into an LDS slot, hi/lo split.
// Per part: [c][136], data at els [4,132); halo els stay zero.
__device__ __forceinline__ void stage_row(u16* slot, int partStride,
                                          const float* __restrict__ img,
                                          int C, int r, bool valid,
                                          int tid, int nthr) {
  for (int idx = tid; idx < C * 16; idx += nthr) {
    int c = idx >> 4, m = idx & 15;
    float v[8];
    if (valid) {
      const float* p = img + ((size_t)c * 128 + r) * 128 + m * 8;
      float4 a = *(const float4*)p;
      float4 b = *(const float4*)(p + 4);
      v[0]=a.x; v[1]=a.y; v[2]=a.z; v[3]=a.w; v[4]=b.x; v[5]=b.y; v[6]=b.z; v[7]=b.w;
    } else {
      #pragma unroll
      for (int k = 0; k < 8; ++k) v[k] = 0.0f;
    }
    union { u16 s[8]; uint2 d[2]; } hh, ll;
    #pragma unroll
    for (int k = 0; k < 8; ++k) {
      u16 h = f2bf(v[k]);
      hh.s[k] = h;
      ll.s[k] = f2bf(v[k] - bf2f(h));
    }
    u16* dh = slot + c * 136 + 4 + m * 8;
    *(uint2*)(dh)     = hh.d[0];
    *(uint2*)(dh + 4) = hh.d[1];
    u16* dl = dh + partStride;
    *(uint2*)(dl)     = ll.d[0];
    *(uint2*)(dl + 4) = ll.d[1];
  }
}

#define SLOT_US 8704     // 2 parts * 32 ch * 136
#define PSTR_32 4352
#define YPSTR   8704     // part stride for 64-ch y row

// ---- Rpart[n][chunk][u 0..4][dvi 0..8][c2 32][c1 32] (u-symmetry: du>=0 only)
// grid = 16(n)*16(chunk of 8 rows); block = 10 waves: wave = du*2 + nt.
__global__ __launch_bounds__(640) void k_corrR_mfma(const float* __restrict__ x,
                                                    float* __restrict__ Rpart) {
  __shared__ __align__(16) u16 lds[5 * SLOT_US];   // 87,040 B
  int n  = blockIdx.x >> 4;
  int r0 = (blockIdx.x & 15) << 3;
  int tid = threadIdx.x;
  const float* xn = x + (size_t)n * 32 * 128 * 128;

  if (tid < 320) {      // zero halos: 5 slots * 2 parts * 32 ch
    int s = tid / 64, p = (tid >> 5) & 1, c = tid & 31;
    u16* b = lds + s * SLOT_US + p * PSTR_32 + c * 136;
    uint2 z; z.x = 0; z.y = 0;
    *(uint2*)b = z;
    *(uint2*)(b + 132) = z;
  }
  for (int rr = 0; rr < 5; ++rr) {
    int r = r0 + rr;
    stage_row(lds + (r % 5) * SLOT_US, PSTR_32, xn, 32, r, r < 128, tid, 640);
  }

  int wave = tid >> 6, lane = tid & 63;
  int du = wave >> 1, nt = wave & 1;
  int lm = lane & 15, q = lane >> 4;

  f32x4 acc[9][2];
  #pragma unroll
  for (int dvi = 0; dvi < 9; ++dvi)
    #pragma unroll
    for (int mt = 0; mt < 2; ++mt) acc[dvi][mt] = (f32x4){0.f, 0.f, 0.f, 0.f};

  for (int i = r0; i < r0 + 8; ++i) {
    __syncthreads();
    const u16* A  = lds + (i % 5) * SLOT_US;
    const u16* Bp = lds + ((i + du) % 5) * SLOT_US;
    #pragma unroll
    for (int ks = 0; ks < 4; ++ks) {
      int kb = ks * 32 + q * 8;
      bf16x8 af[2][2];
      #pragma unroll
      for (int pa = 0; pa < 2; ++pa)
        #pragma unroll
        for (int mt = 0; mt < 2; ++mt)
          af[pa][mt] = load8(A + pa * PSTR_32 + (mt * 16 + lm) * 136 + 4 + kb);
      #pragma unroll
      for (int pb = 0; pb < 2; ++pb) {
        const u16* wp = Bp + pb * PSTR_32 + (nt * 16 + lm) * 136 + kb;
        uint4 w0 = *(const uint4*)wp;
        uint4 w1 = *(const uint4*)(wp + 8);
        unsigned w[8] = {w0.x, w0.y, w0.z, w0.w, w1.x, w1.y, w1.z, w1.w};
        #pragma unroll
        for (int dvi = 0; dvi < 9; ++dvi) {
          bf16x8 bf = build_frag(w, dvi);
          #pragma unroll
          for (int mt = 0; mt < 2; ++mt)
            #pragma unroll
            for (int pa = 0; pa < 2; ++pa) {
              if (pa == 1 && pb == 1) continue;   // skip lo*lo
              acc[dvi][mt] = MFMA16(af[pa][mt], bf, acc[dvi][mt]);
            }
        }
      }
    }
    __syncthreads();
    if (i + 1 < r0 + 8) {
      int r = i + 5;
      stage_row(lds + (r % 5) * SLOT_US, PSTR_32, xn, 32, r, r < 128, tid, 640);
    }
  }

  // D layout: col=lm -> c2-in-tile, row=q*4+r -> c1-in-tile. float4 along c1.
  float* Rp = Rpart + (size_t)blockIdx.x * 46080;
  #pragma unroll
  for (int dvi = 0; dvi < 9; ++dvi)
    #pragma unroll
    for (int mt = 0; mt < 2; ++mt) {
      float* dst = Rp + (du * 9 + dvi) * 1024 + (nt * 16 + lm) * 32 + mt * 16 + q * 4;
      *(f32x4*)dst = acc[dvi][mt];
    }
}

__global__ void k_reduceR(const float* __restrict__ part, float* __restrict__ R) {
  int idx = blockIdx.x * 256 + threadIdx.x;   // < 737280
  int n = idx / 46080, rem = idx % 46080;
  const float* p = part + (size_t)n * 16 * 46080 + rem;
  float s = 0.0f;
  #pragma unroll
  for (int c = 0; c < 16; ++c) s += p[(size_t)c * 46080];
  R[idx] = s;
}

// ---- Ppart[n][chunk][ae 25][ci 32][co 64]; block = 10 waves: wave=(du+2)*2+mh
__global__ __launch_bounds__(640) void k_corrP_mfma(const float* __restrict__ x,
                                                    const float* __restrict__ y,
                                                    float* __restrict__ Ppart) {
  __shared__ __align__(16) u16 xs[5 * SLOT_US];   // 87,040 B
  __shared__ __align__(16) u16 ys[2 * YPSTR];     // 34,816 B
  int n  = blockIdx.x >> 4;
  int r0 = (blockIdx.x & 15) << 3;
  int tid = threadIdx.x;
  const float* xn = x + (size_t)n * 32 * 128 * 128;
  const float* yn = y + (size_t)n * 64 * 128 * 128;

  if (tid < 320) {
    int s = tid / 64, p = (tid >> 5) & 1, c = tid & 31;
    u16* b = xs + s * SLOT_US + p * PSTR_32 + c * 136;
    uint2 z; z.x = 0; z.y = 0;
    *(uint2*)b = z;
    *(uint2*)(b + 132) = z;
  }
  for (int rr = -2; rr <= 2; ++rr) {
    int r = r0 + rr;
    stage_row(xs + ((r + 10) % 5) * SLOT_US, PSTR_32, xn, 32, r,
              (r >= 0 && r < 128), tid, 640);
  }
  stage_row(ys, YPSTR, yn, 64, r0, true, tid, 640);

  int wave = tid >> 6, lane = tid & 63;
  int du = (wave >> 1) - 2, mh = wave & 1;
  int lm = lane & 15, q = lane >> 4;

  f32x4 acc[5][2][2];
  #pragma unroll
  for (int dvi = 0; dvi < 5; ++dvi)
    #pragma unroll
    for (int mt = 0; mt < 2; ++mt)
      #pragma unroll
      for (int nt = 0; nt < 2; ++nt)
        acc[dvi][mt][nt] = (f32x4){0.f, 0.f, 0.f, 0.f};

  for (int i = r0; i < r0 + 8; ++i) {
    __syncthreads();
    const u16* Bp = xs + ((i + du + 10) % 5) * SLOT_US;
    #pragma unroll
    for (int ks = 0; ks < 4; ++ks) {
      int kb = ks * 32 + q * 8;
      bf16x8 af[2][2];
      #pragma unroll
      for (int pa = 0; pa < 2; ++pa)
        #pragma unroll
        for (int mt = 0; mt < 2; ++mt)
          af[pa][mt] = load8(ys + pa * YPSTR + (mh * 32 + mt * 16 + lm) * 136 + 4 + kb);
      #pragma unroll
      for (int nt = 0; nt < 2; ++nt)
        #pragma unroll
        for (int pb = 0; pb < 2; ++pb) {
          const u16* wp = Bp + pb * PSTR_32 + (nt * 16 + lm) * 136 + kb;
          uint4 w0 = *(const uint4*)wp;
          uint4 w1 = *(const uint4*)(wp + 8);
          unsigned w[8] = {w0.x, w0.y, w0.z, w0.w, w1.x, w1.y, w1.z, w1.w};
          #pragma unroll
          for (int dvi = 0; dvi < 5; ++dvi) {
            bf16x8 bf = build_frag(w, dvi + 2);
            #pragma unroll
            for (int mt = 0; mt < 2; ++mt)
              #pragma unroll
              for (int pa = 0; pa < 2; ++pa) {
                if (pa == 1 && pb == 1) continue;
                acc[dvi][mt][nt] = MFMA16(af[pa][mt], bf, acc[dvi][mt][nt]);
              }
          }
        }
    }
    __syncthreads();
    if (i + 1 < r0 + 8) {
      int r = i + 3;
      stage_row(xs + ((r + 10) % 5) * SLOT_US, PSTR_32, xn, 32, r,
                (r >= 0 && r < 128), tid, 640);
      stage_row(ys, YPSTR, yn, 64, i + 1, true, tid, 640);
    }
  }

  // D: col=lm -> ci-in-tile, row=q*4+r -> co-in-tile. float4 along co.
  float* Pp = Ppart + (size_t)blockIdx.x * 51200;
  #pragma unroll
  for (int dvi = 0; dvi < 5; ++dvi)
    #pragma unroll
    for (int mt = 0; mt < 2; ++mt)
      #pragma unroll
      for (int nt = 0; nt < 2; ++nt) {
        float* dst = Pp + ((du + 2) * 5 + dvi) * 2048 + (nt * 16 + lm) * 64
                        + mh * 32 + mt * 16 + q * 4;
        *(f32x4*)dst = acc[dvi][mt][nt];
      }
}

// P[n][k][co] = sum_chunk Ppart + a * d^T
__global__ void k_reduceP(const float* __restrict__ part, const float* __restrict__ d,
                          const float* __restrict__ alpha, const float* __restrict__ reg,
                          float* __restrict__ P) {
  int idx = blockIdx.x * 256 + threadIdx.x;   // < 819200
  int n = idx / 51200, rem = idx % 51200;
  int k = rem >> 6, co = rem & 63;
  int ci = k / 25, ae = k % 25;
  const float* p = part + (size_t)n * 16 * 51200 + (ae * 32 + ci) * 64 + co;
  float s = 0.0f;
  #pragma unroll
  for (int c = 0; c < 16; ++c) s += p[(size_t)c * 51200];
  float a = alpha_scale(alpha, reg, n);
  P[idx] = s + a * d[((size_t)n * 64 + co) * 800 + k];
}

// -------- Q[n,k1,k2] = R_func(c1,c2,b-a,f-e) (+ alpha on diag), symmetric R --
__global__ void k_buildQ(const float* __restrict__ R, float* __restrict__ Q,
                         const float* __restrict__ alpha, const float* __restrict__ reg) {
  int bid = blockIdx.x;
  int n = bid / 800, k1 = bid % 800;
  int c1 = k1 / 25, r1 = k1 % 25, a = r1 / 5, e = r1 % 5;
  float av = alpha_scale(alpha, reg, n);
  const float* Rn = R + (size_t)n * 45 * 1024;
  float* Qrow = Q + ((size_t)n * 800 + k1) * 800;
  for (int k2 = threadIdx.x; k2 < 800; k2 += 256) {
    int c2 = k2 / 25, r2 = k2 % 25, b = r2 / 5, f = r2 % 5;
    int du = b - a, dv = f - e;
    float v = (du >= 0)
      ? Rn[(du * 9 + dv + 4) * 1024 + c2 * 32 + c1]
      : Rn[((-du) * 9 + 4 - dv) * 1024 + c1 * 32 + c2];
    if (k2 == k1) v += av;
    Qrow[k2] = v;
  }
}

// -------------------- Cholesky: diag factor + explicit inverse --------------
__global__ __launch_bounds__(256) void k_chol_diag(float* __restrict__ Q,
                                                   float* __restrict__ Linv, int t) {
  int n = blockIdx.x;
  int tid = threadIdx.x;
  __shared__ float A[80*81];
  __shared__ float B[80*81];
  float* Qn = Q + (size_t)n * 640000;
  int base = t * 80;
  for (int idx = tid; idx < 6400; idx += 256) {
    int r = idx / 80, c = idx % 80;
    A[r*81 + c] = Qn[(base + r)*800 + base + c];
  }
  __syncthreads();
  for (int j = 0; j < 80; ++j) {
    if (tid == 0) A[j*81 + j] = sqrtf(A[j*81 + j]);
    __syncthreads();
    float dinv = 1.0f / A[j*81 + j];
    for (int i = j + 1 + tid; i < 80; i += 256) A[i*81 + j] *= dinv;
    __syncthreads();
    int m = 79 - j;
    for (int idx = tid; idx < m*m; idx += 256) {
      int i = j + 1 + idx / m, k = j + 1 + idx % m;
      if (k <= i) A[i*81 + k] -= A[i*81 + j] * A[k*81 + j];
    }
    __syncthreads();
  }
  if (tid < 80) {
    int j = tid;
    B[j*81 + j] = 1.0f / A[j*81 + j];
    for (int i = j + 1; i < 80; ++i) {
      float s = 0.0f;
      for (int k = j; k < i; ++k) s += A[i*81 + k] * B[k*81 + j];
      B[i*81 + j] = -s / A[i*81 + i];
    }
  }
  __syncthreads();
  float* Ln = Linv + ((size_t)n*10 + t) * 6400;
  for (int idx = tid; idx < 6400; idx += 256) {
    int r = idx / 80, c = idx % 80;
    Ln[idx] = (r >= c) ? B[r*81 + c] : 0.0f;
  }
}

// panel: W = A_panel * Linv^T  (overwrites panel with L)
__global__ __launch_bounds__(256) void k_chol_panel(float* __restrict__ Q,
                                                    const float* __restrict__ Linv,
                                                    int t, int nt) {
  int n = blockIdx.x / nt, it = blockIdx.x % nt;
  int R0 = 80*(t+1) + 80*it, C0 = 80*t;
  __shared__ float As[80*82];
  __shared__ float Bs[80*82];
  float* Qn = Q + (size_t)n * 640000;
  const float* Ln = Linv + ((size_t)n*10 + t) * 6400;
  int tid = threadIdx.x;
  for (int idx = tid; idx < 6400; idx += 256) {
    int r = idx / 80, c = idx % 80;
    As[r*82 + c] = Qn[(R0 + r)*800 + C0 + c];
    Bs[r*82 + c] = Ln[idx];
  }
  __syncthreads();
  int tc = tid & 15, tr = tid >> 4;
  float acc[5][5];
  #pragma unroll
  for (int a = 0; a < 5; ++a)
    #pragma unroll
    for (int b = 0; b < 5; ++b) acc[a][b] = 0.0f;
  for (int k = 0; k < 80; ++k) {
    float av[5], bv[5];
    #pragma unroll
    for (int d = 0; d < 5; ++d) { av[d] = As[(5*tr + d)*82 + k]; bv[d] = Bs[(5*tc + d)*82 + k]; }
    #pragma unroll
    for (int a = 0; a < 5; ++a)
      #pragma unroll
      for (int b = 0; b < 5; ++b) acc[a][b] += av[a] * bv[b];
  }
  #pragma unroll
  for (int a = 0; a < 5; ++a)
    #pragma unroll
    for (int b = 0; b < 5; ++b)
      Qn[(R0 + 5*tr + a)*800 + C0 + 5*tc + b] = acc[a][b];
}

// trailing: A_IJ -= W_I * W_J^T (lower tiles only)
__global__ __launch_bounds__(256) void k_chol_trail(float* __restrict__ Q, int t, int nt) {
  int ntile = nt * (nt + 1) / 2;
  int n = blockIdx.x / ntile;
  int rr = blockIdx.x % ntile;
  int i = 0;
  while (rr >= i + 1) { rr -= (i + 1); ++i; }
  int j = rr;
  int R0 = 80*(t+1+i), C0 = 80*(t+1+j), K0 = 80*t;
  __shared__ float Ws[80*82];
  __shared__ float Vs[80*82];
  float* Qn = Q + (size_t)n * 640000;
  int tid = threadIdx.x;
  for (int idx = tid; idx < 6400; idx += 256) {
    int r = idx / 80, c = idx % 80;
    Ws[r*82 + c] = Qn[(R0 + r)*800 + K0 + c];
    Vs[r*82 + c] = Qn[(C0 + r)*800 + K0 + c];
  }
  __syncthreads();
  int tc = tid & 15, tr = tid >> 4;
  float acc[5][5];
  #pragma unroll
  for (int a = 0; a < 5; ++a)
    #pragma unroll
    for (int b = 0; b < 5; ++b) acc[a][b] = 0.0f;
  for (int k = 0; k < 80; ++k) {
    float av[5], bv[5];
    #pragma unroll
    for (int d = 0; d < 5; ++d) { av[d] = Ws[(5*tr + d)*82 + k]; bv[d] = Vs[(5*tc + d)*82 + k]; }
    #pragma unroll
    for (int a = 0; a < 5; ++a)
      #pragma unroll
      for (int b = 0; b < 5; ++b) acc[a][b] += av[a] * bv[b];
  }
  #pragma unroll
  for (int a = 0; a < 5; ++a)
    #pragma unroll
    for (int b = 0; b < 5; ++b)
      Qn[(R0 + 5*tr + a)*800 + C0 + 5*tc + b] -= acc[a][b];
}

// -------------------- blocked triangular solves + output transpose ---------
__global__ __launch_bounds__(256) void k_solve(const float* __restrict__ Q,
                                               const float* __restrict__ Linv,
                                               const float* __restrict__ P,
                                               float* __restrict__ out) {
  int n = blockIdx.x >> 3;
  int g = blockIdx.x & 7;
  int tid = threadIdx.x;
  __shared__ float z[800*8];
  __shared__ float Lt[80*82];
  const float* Qn = Q + (size_t)n * 640000;

  for (int idx = tid; idx < 6400; idx += 256) {
    int k = idx >> 3, c = idx & 7;
    z[idx] = P[(n*800 + k)*64 + g*8 + c];
  }
  __syncthreads();

  for (int t = 0; t < 10; ++t) {
    for (int s = 0; s < t; ++s) {
      for (int idx = tid; idx < 6400; idx += 256)
        Lt[(idx/80)*82 + (idx%80)] = Qn[(80*t + idx/80)*800 + 80*s + idx%80];
      __syncthreads();
      for (int e = 0; e < 3; ++e) {
        int idx = tid + 256*e;
        if (idx < 640) {
          int c = idx & 7, r = idx >> 3;
          float acc = 0.0f;
          #pragma unroll 4
          for (int k = 0; k < 80; ++k) acc += Lt[r*82 + k] * z[(80*s + k)*8 + c];
          z[(80*t + r)*8 + c] -= acc;
        }
      }
      __syncthreads();
    }
    {
      const float* Ln = Linv + ((size_t)n*10 + t) * 6400;
      for (int idx = tid; idx < 6400; idx += 256)
        Lt[(idx/80)*82 + (idx%80)] = Ln[idx];
      __syncthreads();
      float tv[3];
      for (int e = 0; e < 3; ++e) {
        int idx = tid + 256*e;
        if (idx < 640) {
          int c = idx & 7, r = idx >> 3;
          float acc = 0.0f;
          #pragma unroll 4
          for (int k = 0; k < 80; ++k) acc += Lt[r*82 + k] * z[(80*t + k)*8 + c];
          tv[e] = acc;
        }
      }
      __syncthreads();
      for (int e = 0; e < 3; ++e) {
        int idx = tid + 256*e;
        if (idx < 640) { int c = idx & 7, r = idx >> 3; z[(80*t + r)*8 + c] = tv[e]; }
      }
      __syncthreads();
    }
  }

  for (int t = 9; t >= 0; --t) {
    for (int s = t + 1; s < 10; ++s) {
      for (int idx = tid; idx < 6400; idx += 256)
        Lt[(idx/80)*82 + (idx%80)] = Qn[(80*s + idx/80)*800 + 80*t + idx%80];
      __syncthreads();
      for (int e = 0; e < 3; ++e) {
        int idx = tid + 256*e;
        if (idx < 640) {
          int c = idx & 7, r = idx >> 3;
          float acc = 0.0f;
          #pragma unroll 4
          for (int k = 0; k < 80; ++k) acc += Lt[k*82 + r] * z[(80*s + k)*8 + c];
          z[(80*t + r)*8 + c] -= acc;
        }
      }
      __syncthreads();
    }
    {
      const float* Ln = Linv + ((size_t)n*10 + t) * 6400;
      for (int idx = tid; idx < 6400; idx += 256)
        Lt[(idx/80)*82 + (idx%80)] = Ln[idx];
      __syncthreads();
      float tv[3];
      for (int e = 0; e < 3; ++e) {
        int idx = tid + 256*e;
        if (idx < 640) {
          int c = idx & 7, r = idx >> 3;
          float acc = 0.0f;
          #pragma unroll 4
          for (int k = 0; k < 80; ++k) acc += Lt[k*82 + r] * z[(80*t + k)*8 + c];
          tv[e] = acc;
        }
      }
      __syncthreads();
      for (int e = 0; e < 3; ++e) {
        int idx = tid + 256*e;
        if (idx < 640) { int c = idx & 7, r = idx >> 3; z[(80*t + r)*8 + c] = tv[e]; }
      }
      __syncthreads();
    }
  }

  for (int idx = tid; idx < 6400; idx += 256) {
    int c = idx / 800, k = idx % 800;
    out[(size_t)(n*64 + g*8 + c)*800 + k] = z[k*8 + c];
  }
}

extern "C" void kernel_launch(void* const* d_in, const int* in_sizes, int n_in,
                              void* d_out, int out_size, void* d_ws, size_t ws_size,
                              hipStream_t stream) {
  const float* x     = (const float*)d_in[0];
  const float* d     = (const float*)d_in[1];
  const float* y     = (const float*)d_in[2];
  const float* alpha = (const float*)d_in[3];
  const float* reg   = (const float*)d_in[4];
  float* out = (float*)d_out;
  float* ws  = (float*)d_ws;

  float* R    = ws;                 // R_SZ
  float* Q    = R + R_SZ;           // Q_SZ
  float* P    = Q + Q_SZ;           // P_SZ
  float* Li   = P + P_SZ;           // LI_SZ
  float* part = Li + LI_SZ;         // PART_SZ (reused by corrR then corrP)

  k_corrR_mfma<<<256, 640, 0, stream>>>(x, part);
  k_reduceR<<<R_SZ / 256, 256, 0, stream>>>(part, R);
  k_corrP_mfma<<<256, 640, 0, stream>>>(x, y, part);
  k_reduceP<<<P_SZ / 256, 256, 0, stream>>>(part, d, alpha, reg, P);
  k_buildQ<<<16 * 800, 256, 0, stream>>>(R, Q, alpha, reg);

  for (int t = 0; t < 10; ++t) {
    k_chol_diag<<<16, 256, 0, stream>>>(Q, Li, t);
    int nt = 9 - t;
    if (nt > 0) {
      k_chol_panel<<<16*nt, 256, 0, stream>>>(Q, Li, t, nt);
      k_chol_trail<<<16*nt*(nt+1)/2, 256, 0, stream>>>(Q, t, nt);
    }
  }

  k_solve<<<128, 256, 0, stream>>>(Q, Li, P, out);
}

// Round 5
// 2824.934 us; speedup vs baseline: 1.7809x; 1.1224x over previous
//
#include <hip/hip_runtime.h>

// Problem constants: N=16, C_IN=32, C_OUT=64, H=W=128, D=5, K=800
#define R_SZ    737280           // 16 * 5(u) * 9(v) * 32 * 32
#define Q_SZ    10240000         // 16*800*800
#define P_SZ    819200           // 16*800*64
#define LI_SZ   1024000          // 16*10*80*80
#define PART_SZ 13107200         // max(Rpart 16*16*46080, Ppart 16*16*51200); LiT overlays here

typedef unsigned short u16;
typedef __attribute__((ext_vector_type(8))) short bf16x8;
typedef __attribute__((ext_vector_type(4))) float f32x4;

#define MFMA16(a, b, c) __builtin_amdgcn_mfma_f32_16x16x32_bf16(a, b, c, 0, 0, 0)

__device__ __forceinline__ float alpha_scale(const float* alpha, const float* reg, int n) {
  return alpha[n] * (16384.0f * reg[0] / 800.0f);
}

__device__ __forceinline__ u16 f2bf(float f) {
  union { float f; unsigned u; } v; v.f = f;
  unsigned r = v.u + 0x7FFFu + ((v.u >> 16) & 1u);
  return (u16)(r >> 16);
}
__device__ __forceinline__ float bf2f(u16 h) {
  union { unsigned u; float f; } v; v.u = ((unsigned)h) << 16; return v.f;
}

__device__ __forceinline__ bf16x8 load8(const u16* p) {
  union { uint4 d; bf16x8 v; } u;
  u.d = *(const uint4*)p;
  return u.v;
}

__device__ __forceinline__ bf16x8 build_frag(const unsigned* w, int s) {
  union { unsigned u[4]; bf16x8 v; } f;
  int b = s >> 1;
  if (s & 1) {
    #pragma unroll
    for (int k = 0; k < 4; ++k) f.u[k] = (w[b + k] >> 16) | (w[b + k + 1] << 16);
  } else {
    #pragma unroll
    for (int k = 0; k < 4; ++k) f.u[k] = w[b + k];
  }
  return f.v;
}

// Stage one image row (C channels, 128 px) into an LDS slot, hi/lo split.
__device__ __forceinline__ void stage_row(u16* slot, int partStride,
                                          const float* __restrict__ img,
                                          int C, int r, bool valid,
                                          int tid, int nthr) {
  for (int idx = tid; idx < C * 16; idx += nthr) {
    int c = idx >> 4, m = idx & 15;
    float v[8];
    if (valid) {
      const float* p = img + ((size_t)c * 128 + r) * 128 + m * 8;
      float4 a = *(const float4*)p;
      float4 b = *(const float4*)(p + 4);
      v[0]=a.x; v[1]=a.y; v[2]=a.z; v[3]=a.w; v[4]=b.x; v[5]=b.y; v[6]=b.z; v[7]=b.w;
    } else {
      #pragma unroll
      for (int k = 0; k < 8; ++k) v[k] = 0.0f;
    }
    union { u16 s[8]; uint2 d[2]; } hh, ll;
    #pragma unroll
    for (int k = 0; k < 8; ++k) {
      u16 h = f2bf(v[k]);
      hh.s[k] = h;
      ll.s[k] = f2bf(v[k] - bf2f(h));
    }
    u16* dh = slot + c * 136 + 4 + m * 8;
    *(uint2*)(dh)     = hh.d[0];
    *(uint2*)(dh + 4) = hh.d[1];
    u16* dl = dh + partStride;
    *(uint2*)(dl)     = ll.d[0];
    *(uint2*)(dl + 4) = ll.d[1];
  }
}

#define SLOT_US 8704     // 2 parts * 32 ch * 136
#define PSTR_32 4352
#define YPSTR   8704

// ---- Rpart[n][chunk][u 0..4][dvi 0..8][c2 32][c1 32] (du>=0 only)
__global__ __launch_bounds__(640) void k_corrR_mfma(const float* __restrict__ x,
                                                    float* __restrict__ Rpart) {
  __shared__ __align__(16) u16 lds[5 * SLOT_US];
  int n  = blockIdx.x >> 4;
  int r0 = (blockIdx.x & 15) << 3;
  int tid = threadIdx.x;
  const float* xn = x + (size_t)n * 32 * 128 * 128;

  if (tid < 320) {
    int s = tid / 64, p = (tid >> 5) & 1, c = tid & 31;
    u16* b = lds + s * SLOT_US + p * PSTR_32 + c * 136;
    uint2 z; z.x = 0; z.y = 0;
    *(uint2*)b = z;
    *(uint2*)(b + 132) = z;
  }
  for (int rr = 0; rr < 5; ++rr) {
    int r = r0 + rr;
    stage_row(lds + (r % 5) * SLOT_US, PSTR_32, xn, 32, r, r < 128, tid, 640);
  }

  int wave = tid >> 6, lane = tid & 63;
  int du = wave >> 1, nt = wave & 1;
  int lm = lane & 15, q = lane >> 4;

  f32x4 acc[9][2];
  #pragma unroll
  for (int dvi = 0; dvi < 9; ++dvi)
    #pragma unroll
    for (int mt = 0; mt < 2; ++mt) acc[dvi][mt] = (f32x4){0.f, 0.f, 0.f, 0.f};

  for (int i = r0; i < r0 + 8; ++i) {
    __syncthreads();
    const u16* A  = lds + (i % 5) * SLOT_US;
    const u16* Bp = lds + ((i + du) % 5) * SLOT_US;
    #pragma unroll
    for (int ks = 0; ks < 4; ++ks) {
      int kb = ks * 32 + q * 8;
      bf16x8 af[2][2];
      #pragma unroll
      for (int pa = 0; pa < 2; ++pa)
        #pragma unroll
        for (int mt = 0; mt < 2; ++mt)
          af[pa][mt] = load8(A + pa * PSTR_32 + (mt * 16 + lm) * 136 + 4 + kb);
      #pragma unroll
      for (int pb = 0; pb < 2; ++pb) {
        const u16* wp = Bp + pb * PSTR_32 + (nt * 16 + lm) * 136 + kb;
        uint4 w0 = *(const uint4*)wp;
        uint4 w1 = *(const uint4*)(wp + 8);
        unsigned w[8] = {w0.x, w0.y, w0.z, w0.w, w1.x, w1.y, w1.z, w1.w};
        #pragma unroll
        for (int dvi = 0; dvi < 9; ++dvi) {
          bf16x8 bf = build_frag(w, dvi);
          #pragma unroll
          for (int mt = 0; mt < 2; ++mt)
            #pragma unroll
            for (int pa = 0; pa < 2; ++pa) {
              if (pa == 1 && pb == 1) continue;
              acc[dvi][mt] = MFMA16(af[pa][mt], bf, acc[dvi][mt]);
            }
        }
      }
    }
    __syncthreads();
    if (i + 1 < r0 + 8) {
      int r = i + 5;
      stage_row(lds + (r % 5) * SLOT_US, PSTR_32, xn, 32, r, r < 128, tid, 640);
    }
  }

  float* Rp = Rpart + (size_t)blockIdx.x * 46080;
  #pragma unroll
  for (int dvi = 0; dvi < 9; ++dvi)
    #pragma unroll
    for (int mt = 0; mt < 2; ++mt) {
      float* dst = Rp + (du * 9 + dvi) * 1024 + (nt * 16 + lm) * 32 + mt * 16 + q * 4;
      *(f32x4*)dst = acc[dvi][mt];
    }
}

__global__ void k_reduceR(const float* __restrict__ part, float* __restrict__ R) {
  int idx = blockIdx.x * 256 + threadIdx.x;
  int n = idx / 46080, rem = idx % 46080;
  const float* p = part + (size_t)n * 16 * 46080 + rem;
  float s = 0.0f;
  #pragma unroll
  for (int c = 0; c < 16; ++c) s += p[(size_t)c * 46080];
  R[idx] = s;
}

// ---- Ppart[n][chunk][ae 25][ci 32][co 64]
__global__ __launch_bounds__(640) void k_corrP_mfma(const float* __restrict__ x,
                                                    const float* __restrict__ y,
                                                    float* __restrict__ Ppart) {
  __shared__ __align__(16) u16 xs[5 * SLOT_US];
  __shared__ __align__(16) u16 ys[2 * YPSTR];
  int n  = blockIdx.x >> 4;
  int r0 = (blockIdx.x & 15) << 3;
  int tid = threadIdx.x;
  const float* xn = x + (size_t)n * 32 * 128 * 128;
  const float* yn = y + (size_t)n * 64 * 128 * 128;

  if (tid < 320) {
    int s = tid / 64, p = (tid >> 5) & 1, c = tid & 31;
    u16* b = xs + s * SLOT_US + p * PSTR_32 + c * 136;
    uint2 z; z.x = 0; z.y = 0;
    *(uint2*)b = z;
    *(uint2*)(b + 132) = z;
  }
  for (int rr = -2; rr <= 2; ++rr) {
    int r = r0 + rr;
    stage_row(xs + ((r + 10) % 5) * SLOT_US, PSTR_32, xn, 32, r,
              (r >= 0 && r < 128), tid, 640);
  }
  stage_row(ys, YPSTR, yn, 64, r0, true, tid, 640);

  int wave = tid >> 6, lane = tid & 63;
  int du = (wave >> 1) - 2, mh = wave & 1;
  int lm = lane & 15, q = lane >> 4;

  f32x4 acc[5][2][2];
  #pragma unroll
  for (int dvi = 0; dvi < 5; ++dvi)
    #pragma unroll
    for (int mt = 0; mt < 2; ++mt)
      #pragma unroll
      for (int nt = 0; nt < 2; ++nt)
        acc[dvi][mt][nt] = (f32x4){0.f, 0.f, 0.f, 0.f};

  for (int i = r0; i < r0 + 8; ++i) {
    __syncthreads();
    const u16* Bp = xs + ((i + du + 10) % 5) * SLOT_US;
    #pragma unroll
    for (int ks = 0; ks < 4; ++ks) {
      int kb = ks * 32 + q * 8;
      bf16x8 af[2][2];
      #pragma unroll
      for (int pa = 0; pa < 2; ++pa)
        #pragma unroll
        for (int mt = 0; mt < 2; ++mt)
          af[pa][mt] = load8(ys + pa * YPSTR + (mh * 32 + mt * 16 + lm) * 136 + 4 + kb);
      #pragma unroll
      for (int nt = 0; nt < 2; ++nt)
        #pragma unroll
        for (int pb = 0; pb < 2; ++pb) {
          const u16* wp = Bp + pb * PSTR_32 + (nt * 16 + lm) * 136 + kb;
          uint4 w0 = *(const uint4*)wp;
          uint4 w1 = *(const uint4*)(wp + 8);
          unsigned w[8] = {w0.x, w0.y, w0.z, w0.w, w1.x, w1.y, w1.z, w1.w};
          #pragma unroll
          for (int dvi = 0; dvi < 5; ++dvi) {
            bf16x8 bf = build_frag(w, dvi + 2);
            #pragma unroll
            for (int mt = 0; mt < 2; ++mt)
              #pragma unroll
              for (int pa = 0; pa < 2; ++pa) {
                if (pa == 1 && pb == 1) continue;
                acc[dvi][mt][nt] = MFMA16(af[pa][mt], bf, acc[dvi][mt][nt]);
              }
          }
        }
    }
    __syncthreads();
    if (i + 1 < r0 + 8) {
      int r = i + 3;
      stage_row(xs + ((r + 10) % 5) * SLOT_US, PSTR_32, xn, 32, r,
                (r >= 0 && r < 128), tid, 640);
      stage_row(ys, YPSTR, yn, 64, i + 1, true, tid, 640);
    }
  }

  float* Pp = Ppart + (size_t)blockIdx.x * 51200;
  #pragma unroll
  for (int dvi = 0; dvi < 5; ++dvi)
    #pragma unroll
    for (int mt = 0; mt < 2; ++mt)
      #pragma unroll
      for (int nt = 0; nt < 2; ++nt) {
        float* dst = Pp + ((du + 2) * 5 + dvi) * 2048 + (nt * 16 + lm) * 64
                        + mh * 32 + mt * 16 + q * 4;
        *(f32x4*)dst = acc[dvi][mt][nt];
      }
}

__global__ void k_reduceP(const float* __restrict__ part, const float* __restrict__ d,
                          const float* __restrict__ alpha, const float* __restrict__ reg,
                          float* __restrict__ P) {
  int idx = blockIdx.x * 256 + threadIdx.x;
  int n = idx / 51200, rem = idx % 51200;
  int k = rem >> 6, co = rem & 63;
  int ci = k / 25, ae = k % 25;
  const float* p = part + (size_t)n * 16 * 51200 + (ae * 32 + ci) * 64 + co;
  float s = 0.0f;
  #pragma unroll
  for (int c = 0; c < 16; ++c) s += p[(size_t)c * 51200];
  float a = alpha_scale(alpha, reg, n);
  P[idx] = s + a * d[((size_t)n * 64 + co) * 800 + k];
}

// -------- Q build (symmetric R lookup) --------
__global__ void k_buildQ(const float* __restrict__ R, float* __restrict__ Q,
                         const float* __restrict__ alpha, const float* __restrict__ reg) {
  int bid = blockIdx.x;
  int n = bid / 800, k1 = bid % 800;
  int c1 = k1 / 25, r1 = k1 % 25, a = r1 / 5, e = r1 % 5;
  float av = alpha_scale(alpha, reg, n);
  const float* Rn = R + (size_t)n * 45 * 1024;
  float* Qrow = Q + ((size_t)n * 800 + k1) * 800;
  for (int k2 = threadIdx.x; k2 < 800; k2 += 256) {
    int c2 = k2 / 25, r2 = k2 % 25, b = r2 / 5, f = r2 % 5;
    int du = b - a, dv = f - e;
    float v = (du >= 0)
      ? Rn[(du * 9 + dv + 4) * 1024 + c2 * 32 + c1]
      : Rn[((-du) * 9 + 4 - dv) * 1024 + c1 * 32 + c2];
    if (k2 == k1) v += av;
    Qrow[k2] = v;
  }
}

// -------- Cholesky diag: factor + explicit inverse (Linv and LinvT) --------
__global__ __launch_bounds__(256) void k_chol_diag(float* __restrict__ Q,
                                                   float* __restrict__ Linv,
                                                   float* __restrict__ LinvT, int t) {
  int n = blockIdx.x;
  int tid = threadIdx.x;
  __shared__ float A[80*81];
  __shared__ float B[80*81];
  float* Qn = Q + (size_t)n * 640000;
  int base = t * 80;
  for (int idx = tid; idx < 6400; idx += 256) {
    int r = idx / 80, c = idx % 80;
    A[r*81 + c] = Qn[(base + r)*800 + base + c];
  }
  __syncthreads();
  for (int j = 0; j < 80; ++j) {
    if (tid == 0) A[j*81 + j] = sqrtf(A[j*81 + j]);
    __syncthreads();
    float dinv = 1.0f / A[j*81 + j];
    for (int i = j + 1 + tid; i < 80; i += 256) A[i*81 + j] *= dinv;
    __syncthreads();
    int m = 79 - j;
    for (int idx = tid; idx < m*m; idx += 256) {
      int i = j + 1 + idx / m, k = j + 1 + idx % m;
      if (k <= i) A[i*81 + k] -= A[i*81 + j] * A[k*81 + j];
    }
    __syncthreads();
  }
  if (tid < 80) {
    int j = tid;
    B[j*81 + j] = 1.0f / A[j*81 + j];
    for (int i = j + 1; i < 80; ++i) {
      float s = 0.0f;
      for (int k = j; k < i; ++k) s += A[i*81 + k] * B[k*81 + j];
      B[i*81 + j] = -s / A[i*81 + i];
    }
  }
  __syncthreads();
  float* Ln  = Linv  + ((size_t)n*10 + t) * 6400;
  float* LnT = LinvT + ((size_t)n*10 + t) * 6400;
  for (int idx = tid; idx < 6400; idx += 256) {
    int r = idx / 80, c = idx % 80;
    Ln[idx]  = (r >= c) ? B[r*81 + c] : 0.0f;
    LnT[idx] = (c >= r) ? B[c*81 + r] : 0.0f;   // LnT[r][k] = Linv[k][r]
  }
}

// panel: W = A_panel * Linv^T; store W and W^T (upper triangle of Q)
__global__ __launch_bounds__(256) void k_chol_panel(float* __restrict__ Q,
                                                    const float* __restrict__ Linv,
                                                    int t, int nt) {
  int n = blockIdx.x / nt, it = blockIdx.x % nt;
  int R0 = 80*(t+1) + 80*it, C0 = 80*t;
  __shared__ float As[80*82];
  __shared__ float Bs[80*82];
  float* Qn = Q + (size_t)n * 640000;
  const float* Ln = Linv + ((size_t)n*10 + t) * 6400;
  int tid = threadIdx.x;
  for (int idx = tid; idx < 6400; idx += 256) {
    int r = idx / 80, c = idx % 80;
    As[r*82 + c] = Qn[(R0 + r)*800 + C0 + c];
    Bs[r*82 + c] = Ln[idx];
  }
  __syncthreads();
  int tc = tid & 15, tr = tid >> 4;
  float acc[5][5];
  #pragma unroll
  for (int a = 0; a < 5; ++a)
    #pragma unroll
    for (int b = 0; b < 5; ++b) acc[a][b] = 0.0f;
  for (int k = 0; k < 80; ++k) {
    float av[5], bv[5];
    #pragma unroll
    for (int d = 0; d < 5; ++d) { av[d] = As[(5*tr + d)*82 + k]; bv[d] = Bs[(5*tc + d)*82 + k]; }
    #pragma unroll
    for (int a = 0; a < 5; ++a)
      #pragma unroll
      for (int b = 0; b < 5; ++b) acc[a][b] += av[a] * bv[b];
  }
  #pragma unroll
  for (int a = 0; a < 5; ++a)
    #pragma unroll
    for (int b = 0; b < 5; ++b) {
      Qn[(R0 + 5*tr + a)*800 + C0 + 5*tc + b] = acc[a][b];
      Qn[(C0 + 5*tc + b)*800 + R0 + 5*tr + a] = acc[a][b];   // transposed mirror
    }
}

// trailing: A_IJ -= W_I * W_J^T (lower tiles only)
__global__ __launch_bounds__(256) void k_chol_trail(float* __restrict__ Q, int t, int nt) {
  int ntile = nt * (nt + 1) / 2;
  int n = blockIdx.x / ntile;
  int rr = blockIdx.x % ntile;
  int i = 0;
  while (rr >= i + 1) { rr -= (i + 1); ++i; }
  int j = rr;
  int R0 = 80*(t+1+i), C0 = 80*(t+1+j), K0 = 80*t;
  __shared__ float Ws[80*82];
  __shared__ float Vs[80*82];
  float* Qn = Q + (size_t)n * 640000;
  int tid = threadIdx.x;
  for (int idx = tid; idx < 6400; idx += 256) {
    int r = idx / 80, c = idx % 80;
    Ws[r*82 + c] = Qn[(R0 + r)*800 + K0 + c];
    Vs[r*82 + c] = Qn[(C0 + r)*800 + K0 + c];
  }
  __syncthreads();
  int tc = tid & 15, tr = tid >> 4;
  float acc[5][5];
  #pragma unroll
  for (int a = 0; a < 5; ++a)
    #pragma unroll
    for (int b = 0; b < 5; ++b) acc[a][b] = 0.0f;
  for (int k = 0; k < 80; ++k) {
    float av[5], bv[5];
    #pragma unroll
    for (int d = 0; d < 5; ++d) { av[d] = Ws[(5*tr + d)*82 + k]; bv[d] = Vs[(5*tc + d)*82 + k]; }
    #pragma unroll
    for (int a = 0; a < 5; ++a)
      #pragma unroll
      for (int b = 0; b < 5; ++b) acc[a][b] += av[a] * bv[b];
  }
  #pragma unroll
  for (int a = 0; a < 5; ++a)
    #pragma unroll
    for (int b = 0; b < 5; ++b)
      Qn[(R0 + 5*tr + a)*800 + C0 + 5*tc + b] -= acc[a][b];
}

// -------- solve: right-looking blocked, z in LDS, one wave per panel --------
// grid = 32: n = bid>>1, half = bid&1 (cols half*32..+32). block = 640 (10 waves).
#define ZSTR 36
__global__ __launch_bounds__(640) void k_solve(const float* __restrict__ Q,
                                               const float* __restrict__ Linv,
                                               const float* __restrict__ LinvT,
                                               const float* __restrict__ P,
                                               float* __restrict__ out) {
  __shared__ float z[800 * ZSTR];   // 115,200 B
  int n = blockIdx.x >> 1;
  int half = blockIdx.x & 1;
  int tid = threadIdx.x;
  int wave = tid >> 6, lane = tid & 63;
  const float* Qn = Q + (size_t)n * 640000;

  // load z[k][c] = P[n][k][half*32 + c]
  for (int idx = tid; idx < 25600; idx += 640) {
    int k = idx >> 5, c = idx & 31;
    z[k * ZSTR + c] = P[((size_t)n * 800 + k) * 64 + half * 32 + c];
  }

  // diag mapping: row r = wave*8 + (lane>>3), cols cl*4
  int dr = wave * 8 + (lane >> 3);
  int dc = (lane & 7) * 4;
  // update mapping: rows rg*5.., cols cg*8..
  int rg = lane & 15, cg = lane >> 4;

  // ---------------- forward ----------------
  for (int t = 0; t < 10; ++t) {
    __syncthreads();
    // diag: z_t = Linv_t * w_t
    const float* Li = Linv + ((size_t)n * 10 + t) * 6400;
    float d0 = 0.f, d1 = 0.f, d2 = 0.f, d3 = 0.f;
    #pragma unroll 5
    for (int kc = 0; kc < 20; ++kc) {
      float4 lv = *(const float4*)(Li + dr * 80 + kc * 4);
      #pragma unroll
      for (int j = 0; j < 4; ++j) {
        int k = kc * 4 + j;
        float4 zv = *(const float4*)&z[(80 * t + k) * ZSTR + dc];
        float l = (j == 0) ? lv.x : (j == 1) ? lv.y : (j == 2) ? lv.z : lv.w;
        d0 += l * zv.x; d1 += l * zv.y; d2 += l * zv.z; d3 += l * zv.w;
      }
    }
    __syncthreads();
    *(float4*)&z[(80 * t + dr) * ZSTR + dc] = (float4){d0, d1, d2, d3};
    __syncthreads();
    // updates: wave w handles u = t+1+w
    int u = t + 1 + wave;
    if (u <= 9) {
      const float* Lp = Qn + (size_t)(80 * u) * 800 + 80 * t;  // [r][k] stride 800
      float acc[5][8];
      #pragma unroll
      for (int i = 0; i < 5; ++i)
        #pragma unroll
        for (int j = 0; j < 8; ++j) acc[i][j] = 0.0f;
      for (int kc = 0; kc < 20; ++kc) {
        float4 lv[5];
        #pragma unroll
        for (int i = 0; i < 5; ++i)
          lv[i] = *(const float4*)(Lp + (size_t)(rg * 5 + i) * 800 + kc * 4);
        #pragma unroll
        for (int j = 0; j < 4; ++j) {
          int k = kc * 4 + j;
          float4 z0 = *(const float4*)&z[(80 * t + k) * ZSTR + cg * 8];
          float4 z1 = *(const float4*)&z[(80 * t + k) * ZSTR + cg * 8 + 4];
          #pragma unroll
          for (int i = 0; i < 5; ++i) {
            float l = (j == 0) ? lv[i].x : (j == 1) ? lv[i].y : (j == 2) ? lv[i].z : lv[i].w;
            acc[i][0] += l * z0.x; acc[i][1] += l * z0.y;
            acc[i][2] += l * z0.z; acc[i][3] += l * z0.w;
            acc[i][4] += l * z1.x; acc[i][5] += l * z1.y;
            acc[i][6] += l * z1.z; acc[i][7] += l * z1.w;
          }
        }
      }
      #pragma unroll
      for (int i = 0; i < 5; ++i) {
        float* zp = &z[(80 * u + rg * 5 + i) * ZSTR + cg * 8];
        float4 a = *(float4*)zp, b = *(float4*)(zp + 4);
        a.x -= acc[i][0]; a.y -= acc[i][1]; a.z -= acc[i][2]; a.w -= acc[i][3];
        b.x -= acc[i][4]; b.y -= acc[i][5]; b.z -= acc[i][6]; b.w -= acc[i][7];
        *(float4*)zp = a; *(float4*)(zp + 4) = b;
      }
    }
  }

  // ---------------- backward ----------------
  for (int t = 9; t >= 0; --t) {
    __syncthreads();
    const float* Li = LinvT + ((size_t)n * 10 + t) * 6400;   // LiT[r][k] = Linv[k][r]
    float d0 = 0.f, d1 = 0.f, d2 = 0.f, d3 = 0.f;
    #pragma unroll 5
    for (int kc = 0; kc < 20; ++kc) {
      float4 lv = *(const float4*)(Li + dr * 80 + kc * 4);
      #pragma unroll
      for (int j = 0; j < 4; ++j) {
        int k = kc * 4 + j;
        float4 zv = *(const float4*)&z[(80 * t + k) * ZSTR + dc];
        float l = (j == 0) ? lv.x : (j == 1) ? lv.y : (j == 2) ? lv.z : lv.w;
        d0 += l * zv.x; d1 += l * zv.y; d2 += l * zv.z; d3 += l * zv.w;
      }
    }
    __syncthreads();
    *(float4*)&z[(80 * t + dr) * ZSTR + dc] = (float4){d0, d1, d2, d3};
    __syncthreads();
    // updates: wave w handles u = t-1-w; panel (L_tu)^T stored at Q[80u+r][80t+k]
    int u = t - 1 - wave;
    if (u >= 0) {
      const float* Lp = Qn + (size_t)(80 * u) * 800 + 80 * t;
      float acc[5][8];
      #pragma unroll
      for (int i = 0; i < 5; ++i)
        #pragma unroll
        for (int j = 0; j < 8; ++j) acc[i][j] = 0.0f;
      for (int kc = 0; kc < 20; ++kc) {
        float4 lv[5];
        #pragma unroll
        for (int i = 0; i < 5; ++i)
          lv[i] = *(const float4*)(Lp + (size_t)(rg * 5 + i) * 800 + kc * 4);
        #pragma unroll
        for (int j = 0; j < 4; ++j) {
          int k = kc * 4 + j;
          float4 z0 = *(const float4*)&z[(80 * t + k) * ZSTR + cg * 8];
          float4 z1 = *(const float4*)&z[(80 * t + k) * ZSTR + cg * 8 + 4];
          #pragma unroll
          for (int i = 0; i < 5; ++i) {
            float l = (j == 0) ? lv[i].x : (j == 1) ? lv[i].y : (j == 2) ? lv[i].z : lv[i].w;
            acc[i][0] += l * z0.x; acc[i][1] += l * z0.y;
            acc[i][2] += l * z0.z; acc[i][3] += l * z0.w;
            acc[i][4] += l * z1.x; acc[i][5] += l * z1.y;
            acc[i][6] += l * z1.z; acc[i][7] += l * z1.w;
          }
        }
      }
      #pragma unroll
      for (int i = 0; i < 5; ++i) {
        float* zp = &z[(80 * u + rg * 5 + i) * ZSTR + cg * 8];
        float4 a = *(float4*)zp, b = *(float4*)(zp + 4);
        a.x -= acc[i][0]; a.y -= acc[i][1]; a.z -= acc[i][2]; a.w -= acc[i][3];
        b.x -= acc[i][4]; b.y -= acc[i][5]; b.z -= acc[i][6]; b.w -= acc[i][7];
        *(float4*)zp = a; *(float4*)(zp + 4) = b;
      }
    }
  }

  __syncthreads();
  // out[n][half*32 + c][k] = z[k][c]
  for (int idx = tid; idx < 25600; idx += 640) {
    int c = idx / 800, k = idx % 800;
    out[((size_t)n * 64 + half * 32 + c) * 800 + k] = z[k * ZSTR + c];
  }
}

extern "C" void kernel_launch(void* const* d_in, const int* in_sizes, int n_in,
                              void* d_out, int out_size, void* d_ws, size_t ws_size,
                              hipStream_t stream) {
  const float* x     = (const float*)d_in[0];
  const float* d     = (const float*)d_in[1];
  const float* y     = (const float*)d_in[2];
  const float* alpha = (const float*)d_in[3];
  const float* reg   = (const float*)d_in[4];
  float* out = (float*)d_out;
  float* ws  = (float*)d_ws;

  float* R    = ws;                 // R_SZ
  float* Q    = R + R_SZ;           // Q_SZ
  float* P    = Q + Q_SZ;           // P_SZ
  float* Li   = P + P_SZ;           // LI_SZ
  float* part = Li + LI_SZ;         // PART_SZ (corr partials; LiT overlays after reduceP)
  float* LiT  = part;               // safe: chol runs after k_reduceP

  k_corrR_mfma<<<256, 640, 0, stream>>>(x, part);
  k_reduceR<<<R_SZ / 256, 256, 0, stream>>>(part, R);
  k_corrP_mfma<<<256, 640, 0, stream>>>(x, y, part);
  k_reduceP<<<P_SZ / 256, 256, 0, stream>>>(part, d, alpha, reg, P);
  k_buildQ<<<16 * 800, 256, 0, stream>>>(R, Q, alpha, reg);

  for (int t = 0; t < 10; ++t) {
    k_chol_diag<<<16, 256, 0, stream>>>(Q, Li, LiT, t);
    int nt = 9 - t;
    if (nt > 0) {
      k_chol_panel<<<16*nt, 256, 0, stream>>>(Q, Li, t, nt);
      k_chol_trail<<<16*nt*(nt+1)/2, 256, 0, stream>>>(Q, t, nt);
    }
  }

  k_solve<<<32, 640, 0, stream>>>(Q, Li, LiT, P, out);
}

// Round 6
// 2573.293 us; speedup vs baseline: 1.9551x; 1.0978x over previous
//
#include <hip/hip_runtime.h>
#include <hip/hip_cooperative_groups.h>

namespace cg = cooperative_groups;

// Problem constants: N=16, C_IN=32, C_OUT=64, H=W=128, D=5, K=800
#define R_SZ    737280           // 16 * 5(u) * 9(v) * 32 * 32
#define Q_SZ    10240000         // 16*800*800
#define P_SZ    819200           // 16*800*64
#define LI_SZ   1024000          // 16*10*80*80

typedef unsigned short u16;
typedef __attribute__((ext_vector_type(8))) short bf16x8;
typedef __attribute__((ext_vector_type(4))) float f32x4;

#define MFMA16(a, b, c) __builtin_amdgcn_mfma_f32_16x16x32_bf16(a, b, c, 0, 0, 0)

__device__ __forceinline__ float alpha_scale(const float* alpha, const float* reg, int n) {
  return alpha[n] * (16384.0f * reg[0] / 800.0f);
}

__device__ __forceinline__ u16 f2bf(float f) {
  union { float f; unsigned u; } v; v.f = f;
  unsigned r = v.u + 0x7FFFu + ((v.u >> 16) & 1u);
  return (u16)(r >> 16);
}
__device__ __forceinline__ float bf2f(u16 h) {
  union { unsigned u; float f; } v; v.u = ((unsigned)h) << 16; return v.f;
}

__device__ __forceinline__ bf16x8 load8(const u16* p) {
  union { uint4 d; bf16x8 v; } u;
  u.d = *(const uint4*)p;
  return u.v;
}

__device__ __forceinline__ bf16x8 build_frag(const unsigned* w, int s) {
  union { unsigned u[4]; bf16x8 v; } f;
  int b = s >> 1;
  if (s & 1) {
    #pragma unroll
    for (int k = 0; k < 4; ++k) f.u[k] = (w[b + k] >> 16) | (w[b + k + 1] << 16);
  } else {
    #pragma unroll
    for (int k = 0; k < 4; ++k) f.u[k] = w[b + k];
  }
  return f.v;
}

// Stage one image row (C channels, 128 px) into an LDS slot, hi/lo split.
__device__ __forceinline__ void stage_row(u16* slot, int partStride,
                                          const float* __restrict__ img,
                                          int C, int r, bool valid,
                                          int tid, int nthr) {
  for (int idx = tid; idx < C * 16; idx += nthr) {
    int c = idx >> 4, m = idx & 15;
    float v[8];
    if (valid) {
      const float* p = img + ((size_t)c * 128 + r) * 128 + m * 8;
      float4 a = *(const float4*)p;
      float4 b = *(const float4*)(p + 4);
      v[0]=a.x; v[1]=a.y; v[2]=a.z; v[3]=a.w; v[4]=b.x; v[5]=b.y; v[6]=b.z; v[7]=b.w;
    } else {
      #pragma unroll
      for (int k = 0; k < 8; ++k) v[k] = 0.0f;
    }
    union { u16 s[8]; uint2 d[2]; } hh, ll;
    #pragma unroll
    for (int k = 0; k < 8; ++k) {
      u16 h = f2bf(v[k]);
      hh.s[k] = h;
      ll.s[k] = f2bf(v[k] - bf2f(h));
    }
    u16* dh = slot + c * 136 + 4 + m * 8;
    *(uint2*)(dh)     = hh.d[0];
    *(uint2*)(dh + 4) = hh.d[1];
    u16* dl = dh + partStride;
    *(uint2*)(dl)     = ll.d[0];
    *(uint2*)(dl + 4) = ll.d[1];
  }
}

#define SLOT_US 8704     // 2 parts * 32 ch * 136
#define PSTR_32 4352
#define YPSTR   8704

// ---- Rpart[n][chunk][u 0..4][dvi 0..8][c2 32][c1 32] (du>=0 only)
__global__ __launch_bounds__(640) void k_corrR_mfma(const float* __restrict__ x,
                                                    float* __restrict__ Rpart) {
  __shared__ __align__(16) u16 lds[5 * SLOT_US];
  int n  = blockIdx.x >> 4;
  int r0 = (blockIdx.x & 15) << 3;
  int tid = threadIdx.x;
  const float* xn = x + (size_t)n * 32 * 128 * 128;

  if (tid < 320) {
    int s = tid / 64, p = (tid >> 5) & 1, c = tid & 31;
    u16* b = lds + s * SLOT_US + p * PSTR_32 + c * 136;
    uint2 z; z.x = 0; z.y = 0;
    *(uint2*)b = z;
    *(uint2*)(b + 132) = z;
  }
  for (int rr = 0; rr < 5; ++rr) {
    int r = r0 + rr;
    stage_row(lds + (r % 5) * SLOT_US, PSTR_32, xn, 32, r, r < 128, tid, 640);
  }

  int wave = tid >> 6, lane = tid & 63;
  int du = wave >> 1, nt = wave & 1;
  int lm = lane & 15, q = lane >> 4;

  f32x4 acc[9][2];
  #pragma unroll
  for (int dvi = 0; dvi < 9; ++dvi)
    #pragma unroll
    for (int mt = 0; mt < 2; ++mt) acc[dvi][mt] = (f32x4){0.f, 0.f, 0.f, 0.f};

  for (int i = r0; i < r0 + 8; ++i) {
    __syncthreads();
    const u16* A  = lds + (i % 5) * SLOT_US;
    const u16* Bp = lds + ((i + du) % 5) * SLOT_US;
    #pragma unroll
    for (int ks = 0; ks < 4; ++ks) {
      int kb = ks * 32 + q * 8;
      bf16x8 af[2][2];
      #pragma unroll
      for (int pa = 0; pa < 2; ++pa)
        #pragma unroll
        for (int mt = 0; mt < 2; ++mt)
          af[pa][mt] = load8(A + pa * PSTR_32 + (mt * 16 + lm) * 136 + 4 + kb);
      #pragma unroll
      for (int pb = 0; pb < 2; ++pb) {
        const u16* wp = Bp + pb * PSTR_32 + (nt * 16 + lm) * 136 + kb;
        uint4 w0 = *(const uint4*)wp;
        uint4 w1 = *(const uint4*)(wp + 8);
        unsigned w[8] = {w0.x, w0.y, w0.z, w0.w, w1.x, w1.y, w1.z, w1.w};
        #pragma unroll
        for (int dvi = 0; dvi < 9; ++dvi) {
          bf16x8 bf = build_frag(w, dvi);
          #pragma unroll
          for (int mt = 0; mt < 2; ++mt)
            #pragma unroll
            for (int pa = 0; pa < 2; ++pa) {
              if (pa == 1 && pb == 1) continue;
              acc[dvi][mt] = MFMA16(af[pa][mt], bf, acc[dvi][mt]);
            }
        }
      }
    }
    __syncthreads();
    if (i + 1 < r0 + 8) {
      int r = i + 5;
      stage_row(lds + (r % 5) * SLOT_US, PSTR_32, xn, 32, r, r < 128, tid, 640);
    }
  }

  float* Rp = Rpart + (size_t)blockIdx.x * 46080;
  #pragma unroll
  for (int dvi = 0; dvi < 9; ++dvi)
    #pragma unroll
    for (int mt = 0; mt < 2; ++mt) {
      float* dst = Rp + (du * 9 + dvi) * 1024 + (nt * 16 + lm) * 32 + mt * 16 + q * 4;
      *(f32x4*)dst = acc[dvi][mt];
    }
}

__global__ void k_reduceR(const float* __restrict__ part, float* __restrict__ R) {
  int idx = blockIdx.x * 256 + threadIdx.x;
  int n = idx / 46080, rem = idx % 46080;
  const float* p = part + (size_t)n * 16 * 46080 + rem;
  float s = 0.0f;
  #pragma unroll
  for (int c = 0; c < 16; ++c) s += p[(size_t)c * 46080];
  R[idx] = s;
}

// ---- Ppart[n][chunk][ae 25][ci 32][co 64]
__global__ __launch_bounds__(640) void k_corrP_mfma(const float* __restrict__ x,
                                                    const float* __restrict__ y,
                                                    float* __restrict__ Ppart) {
  __shared__ __align__(16) u16 xs[5 * SLOT_US];
  __shared__ __align__(16) u16 ys[2 * YPSTR];
  int n  = blockIdx.x >> 4;
  int r0 = (blockIdx.x & 15) << 3;
  int tid = threadIdx.x;
  const float* xn = x + (size_t)n * 32 * 128 * 128;
  const float* yn = y + (size_t)n * 64 * 128 * 128;

  if (tid < 320) {
    int s = tid / 64, p = (tid >> 5) & 1, c = tid & 31;
    u16* b = xs + s * SLOT_US + p * PSTR_32 + c * 136;
    uint2 z; z.x = 0; z.y = 0;
    *(uint2*)b = z;
    *(uint2*)(b + 132) = z;
  }
  for (int rr = -2; rr <= 2; ++rr) {
    int r = r0 + rr;
    stage_row(xs + ((r + 10) % 5) * SLOT_US, PSTR_32, xn, 32, r,
              (r >= 0 && r < 128), tid, 640);
  }
  stage_row(ys, YPSTR, yn, 64, r0, true, tid, 640);

  int wave = tid >> 6, lane = tid & 63;
  int du = (wave >> 1) - 2, mh = wave & 1;
  int lm = lane & 15, q = lane >> 4;

  f32x4 acc[5][2][2];
  #pragma unroll
  for (int dvi = 0; dvi < 5; ++dvi)
    #pragma unroll
    for (int mt = 0; mt < 2; ++mt)
      #pragma unroll
      for (int nt = 0; nt < 2; ++nt)
        acc[dvi][mt][nt] = (f32x4){0.f, 0.f, 0.f, 0.f};

  for (int i = r0; i < r0 + 8; ++i) {
    __syncthreads();
    const u16* Bp = xs + ((i + du + 10) % 5) * SLOT_US;
    #pragma unroll
    for (int ks = 0; ks < 4; ++ks) {
      int kb = ks * 32 + q * 8;
      bf16x8 af[2][2];
      #pragma unroll
      for (int pa = 0; pa < 2; ++pa)
        #pragma unroll
        for (int mt = 0; mt < 2; ++mt)
          af[pa][mt] = load8(ys + pa * YPSTR + (mh * 32 + mt * 16 + lm) * 136 + 4 + kb);
      #pragma unroll
      for (int nt = 0; nt < 2; ++nt)
        #pragma unroll
        for (int pb = 0; pb < 2; ++pb) {
          const u16* wp = Bp + pb * PSTR_32 + (nt * 16 + lm) * 136 + kb;
          uint4 w0 = *(const uint4*)wp;
          uint4 w1 = *(const uint4*)(wp + 8);
          unsigned w[8] = {w0.x, w0.y, w0.z, w0.w, w1.x, w1.y, w1.z, w1.w};
          #pragma unroll
          for (int dvi = 0; dvi < 5; ++dvi) {
            bf16x8 bf = build_frag(w, dvi + 2);
            #pragma unroll
            for (int mt = 0; mt < 2; ++mt)
              #pragma unroll
              for (int pa = 0; pa < 2; ++pa) {
                if (pa == 1 && pb == 1) continue;
                acc[dvi][mt][nt] = MFMA16(af[pa][mt], bf, acc[dvi][mt][nt]);
              }
          }
        }
    }
    __syncthreads();
    if (i + 1 < r0 + 8) {
      int r = i + 3;
      stage_row(xs + ((r + 10) % 5) * SLOT_US, PSTR_32, xn, 32, r,
                (r >= 0 && r < 128), tid, 640);
      stage_row(ys, YPSTR, yn, 64, i + 1, true, tid, 640);
    }
  }

  float* Pp = Ppart + (size_t)blockIdx.x * 51200;
  #pragma unroll
  for (int dvi = 0; dvi < 5; ++dvi)
    #pragma unroll
    for (int mt = 0; mt < 2; ++mt)
      #pragma unroll
      for (int nt = 0; nt < 2; ++nt) {
        float* dst = Pp + ((du + 2) * 5 + dvi) * 2048 + (nt * 16 + lm) * 64
                        + mh * 32 + mt * 16 + q * 4;
        *(f32x4*)dst = acc[dvi][mt][nt];
      }
}

__global__ void k_reduceP(const float* __restrict__ part, const float* __restrict__ d,
                          const float* __restrict__ alpha, const float* __restrict__ reg,
                          float* __restrict__ P) {
  int idx = blockIdx.x * 256 + threadIdx.x;
  int n = idx / 51200, rem = idx % 51200;
  int k = rem >> 6, co = rem & 63;
  int ci = k / 25, ae = k % 25;
  const float* p = part + (size_t)n * 16 * 51200 + (ae * 32 + ci) * 64 + co;
  float s = 0.0f;
  #pragma unroll
  for (int c = 0; c < 16; ++c) s += p[(size_t)c * 51200];
  float a = alpha_scale(alpha, reg, n);
  P[idx] = s + a * d[((size_t)n * 64 + co) * 800 + k];
}

// -------- Q build (symmetric R lookup) --------
__global__ void k_buildQ(const float* __restrict__ R, float* __restrict__ Q,
                         const float* __restrict__ alpha, const float* __restrict__ reg) {
  int bid = blockIdx.x;
  int n = bid / 800, k1 = bid % 800;
  int c1 = k1 / 25, r1 = k1 % 25, a = r1 / 5, e = r1 % 5;
  float av = alpha_scale(alpha, reg, n);
  const float* Rn = R + (size_t)n * 45 * 1024;
  float* Qrow = Q + ((size_t)n * 800 + k1) * 800;
  for (int k2 = threadIdx.x; k2 < 800; k2 += 256) {
    int c2 = k2 / 25, r2 = k2 % 25, b = r2 / 5, f = r2 % 5;
    int du = b - a, dv = f - e;
    float v = (du >= 0)
      ? Rn[(du * 9 + dv + 4) * 1024 + c2 * 32 + c1]
      : Rn[((-du) * 9 + 4 - dv) * 1024 + c1 * 32 + c2];
    if (k2 == k1) v += av;
    Qrow[k2] = v;
  }
}

// ======================= cooperative Cholesky =======================
#define DSTR 82

// Factor 80x80 SPD in As (stride DSTR) via 5-wide mini-panels, then build
// Linv in Bs (blocked forward-substitution), write Ln / LnT to global.
// Block-uniform call; 256 threads.
__device__ void diag_factor_invert(float* As, float* Bs, float* Us,
                                   float* __restrict__ Ln, float* __restrict__ LnT,
                                   int tid) {
  for (int s = 0; s < 16; ++s) {
    int base = 5 * s;
    if (tid == 0) {
      #pragma unroll
      for (int j = 0; j < 5; ++j) {
        float dd = sqrtf(As[(base+j)*DSTR + base+j]);
        As[(base+j)*DSTR + base+j] = dd;
        float inv = 1.0f / dd;
        for (int i = j+1; i < 5; ++i) As[(base+i)*DSTR + base+j] *= inv;
        for (int i = j+1; i < 5; ++i)
          for (int k = j+1; k <= i; ++k)
            As[(base+i)*DSTR + base+k] -= As[(base+i)*DSTR + base+j] * As[(base+k)*DSTR + base+j];
      }
    }
    __syncthreads();
    int m = 75 - base;
    for (int r = tid; r < m; r += 256) {
      int row = base + 5 + r;
      float v[5];
      #pragma unroll
      for (int c = 0; c < 5; ++c) v[c] = As[row*DSTR + base + c];
      #pragma unroll
      for (int c = 0; c < 5; ++c) {
        float acc = v[c];
        for (int k = 0; k < c; ++k) acc -= v[k] * As[(base+c)*DSTR + base+k];
        v[c] = acc / As[(base+c)*DSTR + base+c];
      }
      #pragma unroll
      for (int c = 0; c < 5; ++c) As[row*DSTR + base + c] = v[c];
    }
    __syncthreads();
    for (int idx = tid; idx < m*m; idx += 256) {
      int i = idx / m, k = idx % m;
      if (k <= i) {
        float acc = 0.0f;
        #pragma unroll
        for (int c = 0; c < 5; ++c)
          acc += As[(base+5+i)*DSTR + base+c] * As[(base+5+k)*DSTR + base+c];
        As[(base+5+i)*DSTR + base+5+k] -= acc;
      }
    }
    __syncthreads();
  }
  // Linv via blocked forward solve: L * X = I, 5-row groups.
  for (int s = 0; s < 16; ++s) {
    int base = 5 * s;
    for (int idx = tid; idx < 400; idx += 256) {
      int i = idx / 80, j = idx % 80;
      if (j < base) {
        float acc = 0.0f;
        for (int k = j; k < base; ++k)
          acc += As[(base+i)*DSTR + k] * Bs[k*DSTR + j];
        Us[i*DSTR + j] = acc;
      }
    }
    __syncthreads();
    for (int j = tid; j < base + 5; j += 256) {
      float xv[5];
      #pragma unroll
      for (int i = 0; i < 5; ++i) {
        float rhs = (j == base + i ? 1.0f : 0.0f) - (j < base ? Us[i*DSTR + j] : 0.0f);
        for (int kk = 0; kk < i; ++kk) rhs -= As[(base+i)*DSTR + base+kk] * xv[kk];
        xv[i] = rhs / As[(base+i)*DSTR + base+i];
      }
      #pragma unroll
      for (int i = 0; i < 5; ++i) Bs[(base+i)*DSTR + j] = xv[i];
    }
    __syncthreads();
  }
  for (int idx = tid; idx < 6400; idx += 256) {
    int r = idx / 80, c = idx % 80;
    float v = (r >= c) ? Bs[r*DSTR + c] : 0.0f;
    Ln[idx] = v;
    LnT[c*80 + r] = v;
  }
  __syncthreads();
}

__global__ __launch_bounds__(256) void k_chol_coop(float* __restrict__ Q,
                                                   float* __restrict__ Linv,
                                                   float* __restrict__ LinvT) {
  cg::grid_group grid = cg::this_grid();
  __shared__ float S[2 * 80 * DSTR + 5 * DSTR];   // ~54 KB
  float* As = S;
  float* Bs = S + 80 * DSTR;
  float* Us = S + 2 * 80 * DSTR;
  int tid = threadIdx.x;
  int bid = blockIdx.x;
  int tc = tid & 15, tr = tid >> 4;

  // ---- diag(0): blocks 0..15
  if (bid < 16) {
    float* Qn = Q + (size_t)bid * 640000;
    for (int idx = tid; idx < 6400; idx += 256) {
      int r = idx / 80, c = idx % 80;
      As[r*DSTR + c] = Qn[r*800 + c];
    }
    __syncthreads();
    diag_factor_invert(As, Bs, Us,
                       Linv  + (size_t)bid * 10 * 6400,
                       LinvT + (size_t)bid * 10 * 6400, tid);
  }
  grid.sync();

  for (int t = 0; t < 9; ++t) {
    int nt = 9 - t;
    // ---- panel phase: W = A_panel * Linv^T, write W + mirror
    int np = 16 * nt;
    for (int tile = bid; tile < np; tile += gridDim.x) {
      int n = tile / nt, it = tile % nt;
      int R0 = 80*(t+1) + 80*it, C0 = 80*t;
      float* Qn = Q + (size_t)n * 640000;
      const float* Ln = Linv + ((size_t)n*10 + t) * 6400;
      __syncthreads();
      for (int idx = tid; idx < 6400; idx += 256) {
        int r = idx / 80, c = idx % 80;
        As[r*DSTR + c] = Qn[(R0 + r)*800 + C0 + c];
        Bs[r*DSTR + c] = Ln[idx];
      }
      __syncthreads();
      float acc[5][5];
      #pragma unroll
      for (int a = 0; a < 5; ++a)
        #pragma unroll
        for (int b = 0; b < 5; ++b) acc[a][b] = 0.0f;
      for (int k = 0; k < 80; ++k) {
        float av[5], bv[5];
        #pragma unroll
        for (int dd = 0; dd < 5; ++dd) {
          av[dd] = As[(5*tr + dd)*DSTR + k];
          bv[dd] = Bs[(5*tc + dd)*DSTR + k];
        }
        #pragma unroll
        for (int a = 0; a < 5; ++a)
          #pragma unroll
          for (int b = 0; b < 5; ++b) acc[a][b] += av[a] * bv[b];
      }
      #pragma unroll
      for (int a = 0; a < 5; ++a)
        #pragma unroll
        for (int b = 0; b < 5; ++b) {
          Qn[(R0 + 5*tr + a)*800 + C0 + 5*tc + b] = acc[a][b];
          Qn[(C0 + 5*tc + b)*800 + R0 + 5*tr + a] = acc[a][b];
        }
    }
    grid.sync();

    // ---- trail phase (+ inline diag factor of step t+1 on tile (0,0))
    int ntt = nt * (nt + 1) / 2;
    int tt = 16 * ntt;
    for (int tile = bid; tile < tt; tile += gridDim.x) {
      int n = tile / ntt, rr = tile % ntt;
      int i = 0;
      while (rr >= i + 1) { rr -= (i + 1); ++i; }
      int j = rr;
      int R0 = 80*(t+1+i), C0 = 80*(t+1+j), K0 = 80*t;
      float* Qn = Q + (size_t)n * 640000;
      __syncthreads();
      for (int idx = tid; idx < 6400; idx += 256) {
        int r = idx / 80, c = idx % 80;
        As[r*DSTR + c] = Qn[(R0 + r)*800 + K0 + c];
        Bs[r*DSTR + c] = Qn[(C0 + r)*800 + K0 + c];
      }
      __syncthreads();
      float acc[5][5];
      #pragma unroll
      for (int a = 0; a < 5; ++a)
        #pragma unroll
        for (int b = 0; b < 5; ++b) acc[a][b] = 0.0f;
      for (int k = 0; k < 80; ++k) {
        float av[5], bv[5];
        #pragma unroll
        for (int dd = 0; dd < 5; ++dd) {
          av[dd] = As[(5*tr + dd)*DSTR + k];
          bv[dd] = Bs[(5*tc + dd)*DSTR + k];
        }
        #pragma unroll
        for (int a = 0; a < 5; ++a)
          #pragma unroll
          for (int b = 0; b < 5; ++b) acc[a][b] += av[a] * bv[b];
      }
      __syncthreads();   // all LDS reads done before possible overwrite
      bool special = (i == 0 && j == 0);
      #pragma unroll
      for (int a = 0; a < 5; ++a)
        #pragma unroll
        for (int b = 0; b < 5; ++b) {
          float nv = Qn[(R0 + 5*tr + a)*800 + C0 + 5*tc + b] - acc[a][b];
          Qn[(R0 + 5*tr + a)*800 + C0 + 5*tc + b] = nv;
          if (special) As[(5*tr + a)*DSTR + 5*tc + b] = nv;
        }
      if (special) {
        __syncthreads();
        diag_factor_invert(As, Bs, Us,
                           Linv  + ((size_t)n*10 + t + 1) * 6400,
                           LinvT + ((size_t)n*10 + t + 1) * 6400, tid);
      }
    }
    grid.sync();
  }
}

// -------- solve: right-looking blocked, z in LDS, one wave per panel --------
#define ZSTR 36
__global__ __launch_bounds__(640) void k_solve(const float* __restrict__ Q,
                                               const float* __restrict__ Linv,
                                               const float* __restrict__ LinvT,
                                               const float* __restrict__ P,
                                               float* __restrict__ out) {
  __shared__ float z[800 * ZSTR];   // 115,200 B
  int n = blockIdx.x >> 1;
  int half = blockIdx.x & 1;
  int tid = threadIdx.x;
  int wave = tid >> 6, lane = tid & 63;
  const float* Qn = Q + (size_t)n * 640000;

  for (int idx = tid; idx < 25600; idx += 640) {
    int k = idx >> 5, c = idx & 31;
    z[k * ZSTR + c] = P[((size_t)n * 800 + k) * 64 + half * 32 + c];
  }

  int dr = wave * 8 + (lane >> 3);
  int dc = (lane & 7) * 4;
  int rg = lane & 15, cg = lane >> 4;

  for (int t = 0; t < 10; ++t) {
    __syncthreads();
    const float* Li = Linv + ((size_t)n * 10 + t) * 6400;
    float d0 = 0.f, d1 = 0.f, d2 = 0.f, d3 = 0.f;
    #pragma unroll 5
    for (int kc = 0; kc < 20; ++kc) {
      float4 lv = *(const float4*)(Li + dr * 80 + kc * 4);
      #pragma unroll
      for (int j = 0; j < 4; ++j) {
        int k = kc * 4 + j;
        float4 zv = *(const float4*)&z[(80 * t + k) * ZSTR + dc];
        float l = (j == 0) ? lv.x : (j == 1) ? lv.y : (j == 2) ? lv.z : lv.w;
        d0 += l * zv.x; d1 += l * zv.y; d2 += l * zv.z; d3 += l * zv.w;
      }
    }
    __syncthreads();
    *(float4*)&z[(80 * t + dr) * ZSTR + dc] = (float4){d0, d1, d2, d3};
    __syncthreads();
    int u = t + 1 + wave;
    if (u <= 9) {
      const float* Lp = Qn + (size_t)(80 * u) * 800 + 80 * t;
      float acc[5][8];
      #pragma unroll
      for (int i = 0; i < 5; ++i)
        #pragma unroll
        for (int j = 0; j < 8; ++j) acc[i][j] = 0.0f;
      for (int kc = 0; kc < 20; ++kc) {
        float4 lv[5];
        #pragma unroll
        for (int i = 0; i < 5; ++i)
          lv[i] = *(const float4*)(Lp + (size_t)(rg * 5 + i) * 800 + kc * 4);
        #pragma unroll
        for (int j = 0; j < 4; ++j) {
          int k = kc * 4 + j;
          float4 z0 = *(const float4*)&z[(80 * t + k) * ZSTR + cg * 8];
          float4 z1 = *(const float4*)&z[(80 * t + k) * ZSTR + cg * 8 + 4];
          #pragma unroll
          for (int i = 0; i < 5; ++i) {
            float l = (j == 0) ? lv[i].x : (j == 1) ? lv[i].y : (j == 2) ? lv[i].z : lv[i].w;
            acc[i][0] += l * z0.x; acc[i][1] += l * z0.y;
            acc[i][2] += l * z0.z; acc[i][3] += l * z0.w;
            acc[i][4] += l * z1.x; acc[i][5] += l * z1.y;
            acc[i][6] += l * z1.z; acc[i][7] += l * z1.w;
          }
        }
      }
      #pragma unroll
      for (int i = 0; i < 5; ++i) {
        float* zp = &z[(80 * u + rg * 5 + i) * ZSTR + cg * 8];
        float4 a = *(float4*)zp, b = *(float4*)(zp + 4);
        a.x -= acc[i][0]; a.y -= acc[i][1]; a.z -= acc[i][2]; a.w -= acc[i][3];
        b.x -= acc[i][4]; b.y -= acc[i][5]; b.z -= acc[i][6]; b.w -= acc[i][7];
        *(float4*)zp = a; *(float4*)(zp + 4) = b;
      }
    }
  }

  for (int t = 9; t >= 0; --t) {
    __syncthreads();
    const float* Li = LinvT + ((size_t)n * 10 + t) * 6400;
    float d0 = 0.f, d1 = 0.f, d2 = 0.f, d3 = 0.f;
    #pragma unroll 5
    for (int kc = 0; kc < 20; ++kc) {
      float4 lv = *(const float4*)(Li + dr * 80 + kc * 4);
      #pragma unroll
      for (int j = 0; j < 4; ++j) {
        int k = kc * 4 + j;
        float4 zv = *(const float4*)&z[(80 * t + k) * ZSTR + dc];
        float l = (j == 0) ? lv.x : (j == 1) ? lv.y : (j == 2) ? lv.z : lv.w;
        d0 += l * zv.x; d1 += l * zv.y; d2 += l * zv.z; d3 += l * zv.w;
      }
    }
    __syncthreads();
    *(float4*)&z[(80 * t + dr) * ZSTR + dc] = (float4){d0, d1, d2, d3};
    __syncthreads();
    int u = t - 1 - wave;
    if (u >= 0) {
      const float* Lp = Qn + (size_t)(80 * u) * 800 + 80 * t;
      float acc[5][8];
      #pragma unroll
      for (int i = 0; i < 5; ++i)
        #pragma unroll
        for (int j = 0; j < 8; ++j) acc[i][j] = 0.0f;
      for (int kc = 0; kc < 20; ++kc) {
        float4 lv[5];
        #pragma unroll
        for (int i = 0; i < 5; ++i)
          lv[i] = *(const float4*)(Lp + (size_t)(rg * 5 + i) * 800 + kc * 4);
        #pragma unroll
        for (int j = 0; j < 4; ++j) {
          int k = kc * 4 + j;
          float4 z0 = *(const float4*)&z[(80 * t + k) * ZSTR + cg * 8];
          float4 z1 = *(const float4*)&z[(80 * t + k) * ZSTR + cg * 8 + 4];
          #pragma unroll
          for (int i = 0; i < 5; ++i) {
            float l = (j == 0) ? lv[i].x : (j == 1) ? lv[i].y : (j == 2) ? lv[i].z : lv[i].w;
            acc[i][0] += l * z0.x; acc[i][1] += l * z0.y;
            acc[i][2] += l * z0.z; acc[i][3] += l * z0.w;
            acc[i][4] += l * z1.x; acc[i][5] += l * z1.y;
            acc[i][6] += l * z1.z; acc[i][7] += l * z1.w;
          }
        }
      }
      #pragma unroll
      for (int i = 0; i < 5; ++i) {
        float* zp = &z[(80 * u + rg * 5 + i) * ZSTR + cg * 8];
        float4 a = *(float4*)zp, b = *(float4*)(zp + 4);
        a.x -= acc[i][0]; a.y -= acc[i][1]; a.z -= acc[i][2]; a.w -= acc[i][3];
        b.x -= acc[i][4]; b.y -= acc[i][5]; b.z -= acc[i][6]; b.w -= acc[i][7];
        *(float4*)zp = a; *(float4*)(zp + 4) = b;
      }
    }
  }

  __syncthreads();
  for (int idx = tid; idx < 25600; idx += 640) {
    int c = idx / 800, k = idx % 800;
    out[((size_t)n * 64 + half * 32 + c) * 800 + k] = z[k * ZSTR + c];
  }
}

extern "C" void kernel_launch(void* const* d_in, const int* in_sizes, int n_in,
                              void* d_out, int out_size, void* d_ws, size_t ws_size,
                              hipStream_t stream) {
  const float* x     = (const float*)d_in[0];
  const float* d     = (const float*)d_in[1];
  const float* y     = (const float*)d_in[2];
  const float* alpha = (const float*)d_in[3];
  const float* reg   = (const float*)d_in[4];
  float* out = (float*)d_out;
  float* ws  = (float*)d_ws;

  float* R    = ws;                 // R_SZ
  float* Q    = R + R_SZ;           // Q_SZ
  float* P    = Q + Q_SZ;           // P_SZ
  float* Li   = P + P_SZ;           // LI_SZ
  float* part = Li + LI_SZ;         // corr partials; LiT overlays after reduceP
  float* LiT  = part;               // safe: chol runs after k_reduceP

  k_corrR_mfma<<<256, 640, 0, stream>>>(x, part);
  k_reduceR<<<R_SZ / 256, 256, 0, stream>>>(part, R);
  k_corrP_mfma<<<256, 640, 0, stream>>>(x, y, part);
  k_reduceP<<<P_SZ / 256, 256, 0, stream>>>(part, d, alpha, reg, P);
  k_buildQ<<<16 * 800, 256, 0, stream>>>(R, Q, alpha, reg);

  {
    float* Qa = Q; float* La = Li; float* LTa = LiT;
    void* args[] = { &Qa, &La, &LTa };
    hipLaunchCooperativeKernel((void*)k_chol_coop, dim3(256), dim3(256),
                               args, 0, stream);
  }

  k_solve<<<32, 640, 0, stream>>>(Q, Li, LiT, P, out);
}

// Round 7
// 1855.787 us; speedup vs baseline: 2.7109x; 1.3866x over previous
//
#include <hip/hip_runtime.h>

// Problem constants: N=16, C_IN=32, C_OUT=64, H=W=128, D=5, K=800
#define R_SZ    737280           // 16 * 5(u) * 9(v) * 32 * 32
#define Q_SZ    10240000         // 16*800*800
#define P_SZ    819200           // 16*800*64
#define LI_SZ   1024000          // 16*10*80*80
#define W_SZ    4608000          // 16*45*6400

typedef unsigned short u16;
typedef __attribute__((ext_vector_type(8))) short bf16x8;
typedef __attribute__((ext_vector_type(4))) float f32x4;

#define MFMA16(a, b, c) __builtin_amdgcn_mfma_f32_16x16x32_bf16(a, b, c, 0, 0, 0)

__device__ __forceinline__ float alpha_scale(const float* alpha, const float* reg, int n) {
  return alpha[n] * (16384.0f * reg[0] / 800.0f);
}

__device__ __forceinline__ u16 f2bf(float f) {
  union { float f; unsigned u; } v; v.f = f;
  unsigned r = v.u + 0x7FFFu + ((v.u >> 16) & 1u);
  return (u16)(r >> 16);
}
__device__ __forceinline__ float bf2f(u16 h) {
  union { unsigned u; float f; } v; v.u = ((unsigned)h) << 16; return v.f;
}

__device__ __forceinline__ bf16x8 load8(const u16* p) {
  union { uint4 d; bf16x8 v; } u;
  u.d = *(const uint4*)p;
  return u.v;
}

__device__ __forceinline__ bf16x8 build_frag(const unsigned* w, int s) {
  union { unsigned u[4]; bf16x8 v; } f;
  int b = s >> 1;
  if (s & 1) {
    #pragma unroll
    for (int k = 0; k < 4; ++k) f.u[k] = (w[b + k] >> 16) | (w[b + k + 1] << 16);
  } else {
    #pragma unroll
    for (int k = 0; k < 4; ++k) f.u[k] = w[b + k];
  }
  return f.v;
}

// Stage one image row (C channels, 128 px) into an LDS slot, hi/lo split.
__device__ __forceinline__ void stage_row(u16* slot, int partStride,
                                          const float* __restrict__ img,
                                          int C, int r, bool valid,
                                          int tid, int nthr) {
  for (int idx = tid; idx < C * 16; idx += nthr) {
    int c = idx >> 4, m = idx & 15;
    float v[8];
    if (valid) {
      const float* p = img + ((size_t)c * 128 + r) * 128 + m * 8;
      float4 a = *(const float4*)p;
      float4 b = *(const float4*)(p + 4);
      v[0]=a.x; v[1]=a.y; v[2]=a.z; v[3]=a.w; v[4]=b.x; v[5]=b.y; v[6]=b.z; v[7]=b.w;
    } else {
      #pragma unroll
      for (int k = 0; k < 8; ++k) v[k] = 0.0f;
    }
    union { u16 s[8]; uint2 d[2]; } hh, ll;
    #pragma unroll
    for (int k = 0; k < 8; ++k) {
      u16 h = f2bf(v[k]);
      hh.s[k] = h;
      ll.s[k] = f2bf(v[k] - bf2f(h));
    }
    u16* dh = slot + c * 136 + 4 + m * 8;
    *(uint2*)(dh)     = hh.d[0];
    *(uint2*)(dh + 4) = hh.d[1];
    u16* dl = dh + partStride;
    *(uint2*)(dl)     = ll.d[0];
    *(uint2*)(dl + 4) = ll.d[1];
  }
}

#define SLOT_US 8704     // 2 parts * 32 ch * 136
#define PSTR_32 4352
#define YPSTR   8704

// ---- Rpart[n][chunk][u 0..4][dvi 0..8][c2 32][c1 32] (du>=0 only)
__global__ __launch_bounds__(640) void k_corrR_mfma(const float* __restrict__ x,
                                                    float* __restrict__ Rpart) {
  __shared__ __align__(16) u16 lds[5 * SLOT_US];
  int n  = blockIdx.x >> 4;
  int r0 = (blockIdx.x & 15) << 3;
  int tid = threadIdx.x;
  const float* xn = x + (size_t)n * 32 * 128 * 128;

  if (tid < 320) {
    int s = tid / 64, p = (tid >> 5) & 1, c = tid & 31;
    u16* b = lds + s * SLOT_US + p * PSTR_32 + c * 136;
    uint2 z; z.x = 0; z.y = 0;
    *(uint2*)b = z;
    *(uint2*)(b + 132) = z;
  }
  for (int rr = 0; rr < 5; ++rr) {
    int r = r0 + rr;
    stage_row(lds + (r % 5) * SLOT_US, PSTR_32, xn, 32, r, r < 128, tid, 640);
  }

  int wave = tid >> 6, lane = tid & 63;
  int du = wave >> 1, nt = wave & 1;
  int lm = lane & 15, q = lane >> 4;

  f32x4 acc[9][2];
  #pragma unroll
  for (int dvi = 0; dvi < 9; ++dvi)
    #pragma unroll
    for (int mt = 0; mt < 2; ++mt) acc[dvi][mt] = (f32x4){0.f, 0.f, 0.f, 0.f};

  for (int i = r0; i < r0 + 8; ++i) {
    __syncthreads();
    const u16* A  = lds + (i % 5) * SLOT_US;
    const u16* Bp = lds + ((i + du) % 5) * SLOT_US;
    #pragma unroll
    for (int ks = 0; ks < 4; ++ks) {
      int kb = ks * 32 + q * 8;
      bf16x8 af[2][2];
      #pragma unroll
      for (int pa = 0; pa < 2; ++pa)
        #pragma unroll
        for (int mt = 0; mt < 2; ++mt)
          af[pa][mt] = load8(A + pa * PSTR_32 + (mt * 16 + lm) * 136 + 4 + kb);
      #pragma unroll
      for (int pb = 0; pb < 2; ++pb) {
        const u16* wp = Bp + pb * PSTR_32 + (nt * 16 + lm) * 136 + kb;
        uint4 w0 = *(const uint4*)wp;
        uint4 w1 = *(const uint4*)(wp + 8);
        unsigned w[8] = {w0.x, w0.y, w0.z, w0.w, w1.x, w1.y, w1.z, w1.w};
        #pragma unroll
        for (int dvi = 0; dvi < 9; ++dvi) {
          bf16x8 bf = build_frag(w, dvi);
          #pragma unroll
          for (int mt = 0; mt < 2; ++mt)
            #pragma unroll
            for (int pa = 0; pa < 2; ++pa) {
              if (pa == 1 && pb == 1) continue;
              acc[dvi][mt] = MFMA16(af[pa][mt], bf, acc[dvi][mt]);
            }
        }
      }
    }
    __syncthreads();
    if (i + 1 < r0 + 8) {
      int r = i + 5;
      stage_row(lds + (r % 5) * SLOT_US, PSTR_32, xn, 32, r, r < 128, tid, 640);
    }
  }

  float* Rp = Rpart + (size_t)blockIdx.x * 46080;
  #pragma unroll
  for (int dvi = 0; dvi < 9; ++dvi)
    #pragma unroll
    for (int mt = 0; mt < 2; ++mt) {
      float* dst = Rp + (du * 9 + dvi) * 1024 + (nt * 16 + lm) * 32 + mt * 16 + q * 4;
      *(f32x4*)dst = acc[dvi][mt];
    }
}

__global__ void k_reduceR(const float* __restrict__ part, float* __restrict__ R) {
  int idx = blockIdx.x * 256 + threadIdx.x;
  int n = idx / 46080, rem = idx % 46080;
  const float* p = part + (size_t)n * 16 * 46080 + rem;
  float s = 0.0f;
  #pragma unroll
  for (int c = 0; c < 16; ++c) s += p[(size_t)c * 46080];
  R[idx] = s;
}

// ---- Ppart[n][chunk][ae 25][ci 32][co 64]
__global__ __launch_bounds__(640) void k_corrP_mfma(const float* __restrict__ x,
                                                    const float* __restrict__ y,
                                                    float* __restrict__ Ppart) {
  __shared__ __align__(16) u16 xs[5 * SLOT_US];
  __shared__ __align__(16) u16 ys[2 * YPSTR];
  int n  = blockIdx.x >> 4;
  int r0 = (blockIdx.x & 15) << 3;
  int tid = threadIdx.x;
  const float* xn = x + (size_t)n * 32 * 128 * 128;
  const float* yn = y + (size_t)n * 64 * 128 * 128;

  if (tid < 320) {
    int s = tid / 64, p = (tid >> 5) & 1, c = tid & 31;
    u16* b = xs + s * SLOT_US + p * PSTR_32 + c * 136;
    uint2 z; z.x = 0; z.y = 0;
    *(uint2*)b = z;
    *(uint2*)(b + 132) = z;
  }
  for (int rr = -2; rr <= 2; ++rr) {
    int r = r0 + rr;
    stage_row(xs + ((r + 10) % 5) * SLOT_US, PSTR_32, xn, 32, r,
              (r >= 0 && r < 128), tid, 640);
  }
  stage_row(ys, YPSTR, yn, 64, r0, true, tid, 640);

  int wave = tid >> 6, lane = tid & 63;
  int du = (wave >> 1) - 2, mh = wave & 1;
  int lm = lane & 15, q = lane >> 4;

  f32x4 acc[5][2][2];
  #pragma unroll
  for (int dvi = 0; dvi < 5; ++dvi)
    #pragma unroll
    for (int mt = 0; mt < 2; ++mt)
      #pragma unroll
      for (int nt = 0; nt < 2; ++nt)
        acc[dvi][mt][nt] = (f32x4){0.f, 0.f, 0.f, 0.f};

  for (int i = r0; i < r0 + 8; ++i) {
    __syncthreads();
    const u16* Bp = xs + ((i + du + 10) % 5) * SLOT_US;
    #pragma unroll
    for (int ks = 0; ks < 4; ++ks) {
      int kb = ks * 32 + q * 8;
      bf16x8 af[2][2];
      #pragma unroll
      for (int pa = 0; pa < 2; ++pa)
        #pragma unroll
        for (int mt = 0; mt < 2; ++mt)
          af[pa][mt] = load8(ys + pa * YPSTR + (mh * 32 + mt * 16 + lm) * 136 + 4 + kb);
      #pragma unroll
      for (int nt = 0; nt < 2; ++nt)
        #pragma unroll
        for (int pb = 0; pb < 2; ++pb) {
          const u16* wp = Bp + pb * PSTR_32 + (nt * 16 + lm) * 136 + kb;
          uint4 w0 = *(const uint4*)wp;
          uint4 w1 = *(const uint4*)(wp + 8);
          unsigned w[8] = {w0.x, w0.y, w0.z, w0.w, w1.x, w1.y, w1.z, w1.w};
          #pragma unroll
          for (int dvi = 0; dvi < 5; ++dvi) {
            bf16x8 bf = build_frag(w, dvi + 2);
            #pragma unroll
            for (int mt = 0; mt < 2; ++mt)
              #pragma unroll
              for (int pa = 0; pa < 2; ++pa) {
                if (pa == 1 && pb == 1) continue;
                acc[dvi][mt][nt] = MFMA16(af[pa][mt], bf, acc[dvi][mt][nt]);
              }
          }
        }
    }
    __syncthreads();
    if (i + 1 < r0 + 8) {
      int r = i + 3;
      stage_row(xs + ((r + 10) % 5) * SLOT_US, PSTR_32, xn, 32, r,
                (r >= 0 && r < 128), tid, 640);
      stage_row(ys, YPSTR, yn, 64, i + 1, true, tid, 640);
    }
  }

  float* Pp = Ppart + (size_t)blockIdx.x * 51200;
  #pragma unroll
  for (int dvi = 0; dvi < 5; ++dvi)
    #pragma unroll
    for (int mt = 0; mt < 2; ++mt)
      #pragma unroll
      for (int nt = 0; nt < 2; ++nt) {
        float* dst = Pp + ((du + 2) * 5 + dvi) * 2048 + (nt * 16 + lm) * 64
                        + mh * 32 + mt * 16 + q * 4;
        *(f32x4*)dst = acc[dvi][mt][nt];
      }
}

__global__ void k_reduceP(const float* __restrict__ part, const float* __restrict__ d,
                          const float* __restrict__ alpha, const float* __restrict__ reg,
                          float* __restrict__ P) {
  int idx = blockIdx.x * 256 + threadIdx.x;
  int n = idx / 51200, rem = idx % 51200;
  int k = rem >> 6, co = rem & 63;
  int ci = k / 25, ae = k % 25;
  const float* p = part + (size_t)n * 16 * 51200 + (ae * 32 + ci) * 64 + co;
  float s = 0.0f;
  #pragma unroll
  for (int c = 0; c < 16; ++c) s += p[(size_t)c * 51200];
  float a = alpha_scale(alpha, reg, n);
  P[idx] = s + a * d[((size_t)n * 64 + co) * 800 + k];
}

// -------- Q build (symmetric R lookup) --------
__global__ void k_buildQ(const float* __restrict__ R, float* __restrict__ Q,
                         const float* __restrict__ alpha, const float* __restrict__ reg) {
  int bid = blockIdx.x;
  int n = bid / 800, k1 = bid % 800;
  int c1 = k1 / 25, r1 = k1 % 25, a = r1 / 5, e = r1 % 5;
  float av = alpha_scale(alpha, reg, n);
  const float* Rn = R + (size_t)n * 45 * 1024;
  float* Qrow = Q + ((size_t)n * 800 + k1) * 800;
  for (int k2 = threadIdx.x; k2 < 800; k2 += 256) {
    int c2 = k2 / 25, r2 = k2 % 25, b = r2 / 5, f = r2 % 5;
    int du = b - a, dv = f - e;
    float v = (du >= 0)
      ? Rn[(du * 9 + dv + 4) * 1024 + c2 * 32 + c1]
      : Rn[((-du) * 9 + 4 - dv) * 1024 + c1 * 32 + c2];
    if (k2 == k1) v += av;
    Qrow[k2] = v;
  }
}

// ======================= Cholesky (plain kernels) =======================
#define DS 82

// Factor 80x80 SPD (As, stride 82) and write Linv row-major + k-major.
// 256 threads, block-uniform. Bs is LDS scratch (stride 82).
__device__ void diag_factor_invert2(float* As, float* Bs,
                                    float* __restrict__ Ln, float* __restrict__ LnT,
                                    int tid) {
  // --- blocked factorization: 16 strips of 5, redundant 5x5 register factor
  for (int s = 0; s < 16; ++s) {
    int b = 5 * s;
    float a[5][5], dinv[5];
    #pragma unroll
    for (int ii = 0; ii < 5; ++ii)
      #pragma unroll
      for (int kk = 0; kk <= ii; ++kk) a[ii][kk] = As[(b+ii)*DS + b+kk];
    #pragma unroll
    for (int jj = 0; jj < 5; ++jj) {
      float dd = sqrtf(a[jj][jj]);
      a[jj][jj] = dd; dinv[jj] = 1.0f / dd;
      #pragma unroll
      for (int ii = jj+1; ii < 5; ++ii) a[ii][jj] *= dinv[jj];
      #pragma unroll
      for (int ii = jj+1; ii < 5; ++ii)
        #pragma unroll
        for (int kk = jj+1; kk <= ii; ++kk) a[ii][kk] -= a[ii][jj] * a[kk][jj];
    }
    if (tid < 25) {
      int ii = tid / 5, kk = tid % 5;
      if (kk <= ii) As[(b+ii)*DS + b+kk] = a[ii][kk];
    }
    int m = 75 - b;
    // panel row solves (each thread one row)
    for (int r = tid; r < m; r += 256) {
      int row = b + 5 + r;
      float w[5];
      #pragma unroll
      for (int c = 0; c < 5; ++c) {
        float av2 = As[row*DS + b + c];
        #pragma unroll
        for (int kk = 0; kk < c; ++kk) av2 -= w[kk] * a[c][kk];
        w[c] = av2 * dinv[c];
      }
      #pragma unroll
      for (int c = 0; c < 5; ++c) As[row*DS + b + c] = w[c];
    }
    __syncthreads();
    // rank-5 trailing update (lower triangle)
    for (int idx = tid; idx < m*m; idx += 256) {
      int ii = idx / m, kk = idx % m;
      if (kk <= ii) {
        int ri = b+5+ii, rk = b+5+kk;
        float acc2 = As[ri*DS + rk];
        #pragma unroll
        for (int c = 0; c < 5; ++c) acc2 -= As[ri*DS + b+c] * As[rk*DS + b+c];
        As[ri*DS + rk] = acc2;
      }
    }
    __syncthreads();
  }
  // --- inversion: thread j solves column j (LDS-progressive, no reg arrays)
  if (tid < 80) {
    int j = tid;
    for (int ii = j; ii < 80; ++ii) {
      float acc2 = (ii == j) ? 1.0f : 0.0f;
      for (int kk = j; kk < ii; ++kk) acc2 -= As[ii*DS + kk] * Bs[kk*DS + j];
      Bs[ii*DS + j] = acc2 / As[ii*DS + ii];
    }
  }
  __syncthreads();
  for (int idx = tid; idx < 6400; idx += 256) {
    int r = idx / 80, c = idx % 80;
    float v = (r >= c) ? Bs[r*DS + c] : 0.0f;
    Ln[idx] = v;           // row-major
    LnT[c*80 + r] = v;     // k-major: LnT[k*80+i] = Linv[i][k]
  }
}

__global__ __launch_bounds__(256) void k_diag0(const float* __restrict__ Q,
                                               float* __restrict__ Linv,
                                               float* __restrict__ LinvT) {
  __shared__ float As[80*DS];
  __shared__ float Bs[80*DS];
  int n = blockIdx.x, tid = threadIdx.x;
  const float* Qn = Q + (size_t)n * 640000;
  for (int idx = tid; idx < 6400; idx += 256) {
    int r = idx / 80, c = idx % 80;
    As[r*DS + c] = Qn[r*800 + c];
  }
  __syncthreads();
  diag_factor_invert2(As, Bs, Linv + (size_t)n*10*6400, LinvT + (size_t)n*10*6400, tid);
}

// One kernel per step t: each trail tile recomputes its W panels from
// A*Linv^T, (i,i) tiles store W to Wrm (row-major) + Wcm (k-major),
// tile (0,0) inline-factors diag t+1.
__global__ __launch_bounds__(256) void k_chol_step(float* __restrict__ Q,
                                                   float* __restrict__ Linv,
                                                   float* __restrict__ LinvT,
                                                   float* __restrict__ Wrm,
                                                   float* __restrict__ Wcm,
                                                   int t) {
  int nt = 9 - t;
  int T = nt * (nt + 1) / 2;
  int n = blockIdx.x / T;
  int rr = blockIdx.x % T;
  int i = 0;
  while (rr >= i + 1) { rr -= i + 1; ++i; }
  int j = rr;
  int bi = t + 1 + i, bj = t + 1 + j;

  __shared__ float Ls[80*DS];
  __shared__ float Aa[80*DS];
  __shared__ float W1[80*DS];
  __shared__ float W2[80*DS];
  int tid = threadIdx.x, tc = tid & 15, tr = tid >> 4;
  float* Qn = Q + (size_t)n * 640000;
  const float* Ln = Linv + ((size_t)n*10 + t) * 6400;

  for (int idx = tid; idx < 6400; idx += 256) {
    int r = idx / 80, c = idx % 80;
    Ls[r*DS + c] = Ln[idx];
    Aa[r*DS + c] = Qn[(size_t)(80*bi + r)*800 + 80*t + c];
  }
  __syncthreads();

  float acc[5][5];
  // GEMM1: W1 = A_i * Linv^T
  #pragma unroll
  for (int a = 0; a < 5; ++a)
    #pragma unroll
    for (int b = 0; b < 5; ++b) acc[a][b] = 0.0f;
  for (int k = 0; k < 80; ++k) {
    float av[5], bv[5];
    #pragma unroll
    for (int dd = 0; dd < 5; ++dd) { av[dd] = Aa[(5*tr+dd)*DS + k]; bv[dd] = Ls[(5*tc+dd)*DS + k]; }
    #pragma unroll
    for (int a = 0; a < 5; ++a)
      #pragma unroll
      for (int b = 0; b < 5; ++b) acc[a][b] += av[a] * bv[b];
  }
  #pragma unroll
  for (int a = 0; a < 5; ++a)
    #pragma unroll
    for (int b = 0; b < 5; ++b) W1[(5*tr+a)*DS + 5*tc+b] = acc[a][b];
  if (i == j) {
    int p = t*9 - t*(t-1)/2 + i;
    size_t base = ((size_t)n*45 + p) * 6400;
    #pragma unroll
    for (int a = 0; a < 5; ++a)
      #pragma unroll
      for (int b = 0; b < 5; ++b) {
        Wrm[base + (5*tr+a)*80 + 5*tc+b] = acc[a][b];
        Wcm[base + (5*tc+b)*80 + 5*tr+a] = acc[a][b];
      }
  }
  __syncthreads();

  const float* Wia = W1;
  const float* Wjb = W1;
  if (i != j) {
    for (int idx = tid; idx < 6400; idx += 256) {
      int r = idx / 80, c = idx % 80;
      Aa[r*DS + c] = Qn[(size_t)(80*bj + r)*800 + 80*t + c];
    }
    __syncthreads();
    #pragma unroll
    for (int a = 0; a < 5; ++a)
      #pragma unroll
      for (int b = 0; b < 5; ++b) acc[a][b] = 0.0f;
    for (int k = 0; k < 80; ++k) {
      float av[5], bv[5];
      #pragma unroll
      for (int dd = 0; dd < 5; ++dd) { av[dd] = Aa[(5*tr+dd)*DS + k]; bv[dd] = Ls[(5*tc+dd)*DS + k]; }
      #pragma unroll
      for (int a = 0; a < 5; ++a)
        #pragma unroll
        for (int b = 0; b < 5; ++b) acc[a][b] += av[a] * bv[b];
    }
    #pragma unroll
    for (int a = 0; a < 5; ++a)
      #pragma unroll
      for (int b = 0; b < 5; ++b) W2[(5*tr+a)*DS + 5*tc+b] = acc[a][b];
    Wjb = W2;
    __syncthreads();
  }

  // stage A_ij
  for (int idx = tid; idx < 6400; idx += 256) {
    int r = idx / 80, c = idx % 80;
    Aa[r*DS + c] = Qn[(size_t)(80*bi + r)*800 + 80*bj + c];
  }
  __syncthreads();

  // GEMM3: U = Wi * Wj^T ; A_ij -= U
  #pragma unroll
  for (int a = 0; a < 5; ++a)
    #pragma unroll
    for (int b = 0; b < 5; ++b) acc[a][b] = 0.0f;
  for (int k = 0; k < 80; ++k) {
    float av[5], bv[5];
    #pragma unroll
    for (int dd = 0; dd < 5; ++dd) { av[dd] = Wia[(5*tr+dd)*DS + k]; bv[dd] = Wjb[(5*tc+dd)*DS + k]; }
    #pragma unroll
    for (int a = 0; a < 5; ++a)
      #pragma unroll
      for (int b = 0; b < 5; ++b) acc[a][b] += av[a] * bv[b];
  }

  bool special = (i == 0 && j == 0);
  if (!special) {
    #pragma unroll
    for (int a = 0; a < 5; ++a)
      #pragma unroll
      for (int b = 0; b < 5; ++b)
        Qn[(size_t)(80*bi + 5*tr+a)*800 + 80*bj + 5*tc+b] =
          Aa[(5*tr+a)*DS + 5*tc+b] - acc[a][b];
  } else {
    #pragma unroll
    for (int a = 0; a < 5; ++a)
      #pragma unroll
      for (int b = 0; b < 5; ++b)
        Aa[(5*tr+a)*DS + 5*tc+b] -= acc[a][b];
    __syncthreads();
    diag_factor_invert2(Aa, Ls,
                        Linv  + ((size_t)n*10 + t + 1) * 6400,
                        LinvT + ((size_t)n*10 + t + 1) * 6400, tid);
  }
}

// -------- solve: z in LDS; coalesced panel reads via Wcm/Wrm/LinvT/Linv ----
// grid = 64: n = bid>>2, col group (bid&3)*16. block = 640 (10 waves).
#define ZS 20
__global__ __launch_bounds__(640) void k_solve(const float* __restrict__ Linv,
                                               const float* __restrict__ LinvT,
                                               const float* __restrict__ Wrm,
                                               const float* __restrict__ Wcm,
                                               const float* __restrict__ P,
                                               float* __restrict__ out) {
  __shared__ float z[800 * ZS];   // 64,000 B
  int n = blockIdx.x >> 2;
  int qg = (blockIdx.x & 3) * 16;
  int tid = threadIdx.x, wave = tid >> 6, lane = tid & 63;
  int rg = lane & 15, cg = lane >> 4;       // rows rg*5+d
  const float* Lb  = Linv  + (size_t)n*10*6400;
  const float* LTb = LinvT + (size_t)n*10*6400;
  const float* Wr  = Wrm + (size_t)n*45*6400;
  const float* Wc  = Wcm + (size_t)n*45*6400;

  for (int idx = tid; idx < 12800; idx += 640) {
    int k = idx >> 4, c = idx & 15;
    z[k*ZS + c] = P[((size_t)n*800 + k)*64 + qg + c];
  }

  // ---------------- forward ----------------
  for (int t = 0; t < 10; ++t) {
    __syncthreads();
    float dacc[5][2];
    if (wave < 2) {
      const float* LT = LTb + t*6400;
      #pragma unroll
      for (int d = 0; d < 5; ++d) { dacc[d][0] = 0.f; dacc[d][1] = 0.f; }
      int c0 = wave*8 + cg*2;
      for (int k = 0; k < 80; ++k) {
        float a5[5];
        #pragma unroll
        for (int d = 0; d < 5; ++d) a5[d] = LT[k*80 + rg*5 + d];
        float z0 = z[(80*t + k)*ZS + c0];
        float z1 = z[(80*t + k)*ZS + c0 + 1];
        #pragma unroll
        for (int d = 0; d < 5; ++d) { dacc[d][0] += a5[d]*z0; dacc[d][1] += a5[d]*z1; }
      }
    }
    __syncthreads();
    if (wave < 2) {
      int c0 = wave*8 + cg*2;
      #pragma unroll
      for (int d = 0; d < 5; ++d) {
        z[(80*t + rg*5 + d)*ZS + c0]     = dacc[d][0];
        z[(80*t + rg*5 + d)*ZS + c0 + 1] = dacc[d][1];
      }
    }
    __syncthreads();
    int u = t + 1 + wave;
    if (u <= 9) {
      int p = t*9 - t*(t-1)/2 + (u - t - 1);
      const float* A = Wc + (size_t)p * 6400;
      float acc[5][4];
      #pragma unroll
      for (int d = 0; d < 5; ++d)
        #pragma unroll
        for (int e = 0; e < 4; ++e) acc[d][e] = 0.f;
      for (int k = 0; k < 80; ++k) {
        float a5[5];
        #pragma unroll
        for (int d = 0; d < 5; ++d) a5[d] = A[k*80 + rg*5 + d];
        float4 zv = *(const float4*)&z[(80*t + k)*ZS + cg*4];
        #pragma unroll
        for (int d = 0; d < 5; ++d) {
          acc[d][0] += a5[d]*zv.x; acc[d][1] += a5[d]*zv.y;
          acc[d][2] += a5[d]*zv.z; acc[d][3] += a5[d]*zv.w;
        }
      }
      #pragma unroll
      for (int d = 0; d < 5; ++d)
        #pragma unroll
        for (int e = 0; e < 4; ++e)
          z[(80*u + rg*5 + d)*ZS + cg*4 + e] -= acc[d][e];
    }
  }

  // ---------------- backward ----------------
  for (int t = 9; t >= 0; --t) {
    __syncthreads();
    float dacc[5][2];
    if (wave < 2) {
      const float* Li = Lb + t*6400;   // Linv^T[i][k] = Linv[k][i] = Li[k*80+i]
      #pragma unroll
      for (int d = 0; d < 5; ++d) { dacc[d][0] = 0.f; dacc[d][1] = 0.f; }
      int c0 = wave*8 + cg*2;
      for (int k = 0; k < 80; ++k) {
        float a5[5];
        #pragma unroll
        for (int d = 0; d < 5; ++d) a5[d] = Li[k*80 + rg*5 + d];
        float z0 = z[(80*t + k)*ZS + c0];
        float z1 = z[(80*t + k)*ZS + c0 + 1];
        #pragma unroll
        for (int d = 0; d < 5; ++d) { dacc[d][0] += a5[d]*z0; dacc[d][1] += a5[d]*z1; }
      }
    }
    __syncthreads();
    if (wave < 2) {
      int c0 = wave*8 + cg*2;
      #pragma unroll
      for (int d = 0; d < 5; ++d) {
        z[(80*t + rg*5 + d)*ZS + c0]     = dacc[d][0];
        z[(80*t + rg*5 + d)*ZS + c0 + 1] = dacc[d][1];
      }
    }
    __syncthreads();
    int u = t - 1 - wave;
    if (u >= 0) {
      int p = u*9 - u*(u-1)/2 + (t - u - 1);
      const float* A = Wr + (size_t)p * 6400;   // W'[k][i] = L_tu[k][i]
      float acc[5][4];
      #pragma unroll
      for (int d = 0; d < 5; ++d)
        #pragma unroll
        for (int e = 0; e < 4; ++e) acc[d][e] = 0.f;
      for (int k = 0; k < 80; ++k) {
        float a5[5];
        #pragma unroll
        for (int d = 0; d < 5; ++d) a5[d] = A[k*80 + rg*5 + d];
        float4 zv = *(const float4*)&z[(80*t + k)*ZS + cg*4];
        #pragma unroll
        for (int d = 0; d < 5; ++d) {
          acc[d][0] += a5[d]*zv.x; acc[d][1] += a5[d]*zv.y;
          acc[d][2] += a5[d]*zv.z; acc[d][3] += a5[d]*zv.w;
        }
      }
      #pragma unroll
      for (int d = 0; d < 5; ++d)
        #pragma unroll
        for (int e = 0; e < 4; ++e)
          z[(80*u + rg*5 + d)*ZS + cg*4 + e] -= acc[d][e];
    }
  }

  __syncthreads();
  for (int idx = tid; idx < 12800; idx += 640) {
    int c = idx / 800, k = idx % 800;
    out[((size_t)n*64 + qg + c)*800 + k] = z[k*ZS + c];
  }
}

extern "C" void kernel_launch(void* const* d_in, const int* in_sizes, int n_in,
                              void* d_out, int out_size, void* d_ws, size_t ws_size,
                              hipStream_t stream) {
  const float* x     = (const float*)d_in[0];
  const float* d     = (const float*)d_in[1];
  const float* y     = (const float*)d_in[2];
  const float* alpha = (const float*)d_in[3];
  const float* reg   = (const float*)d_in[4];
  float* out = (float*)d_out;
  float* ws  = (float*)d_ws;

  float* R    = ws;                 // R_SZ
  float* Q    = R + R_SZ;           // Q_SZ
  float* P    = Q + Q_SZ;           // P_SZ
  float* Li   = P + P_SZ;           // LI_SZ
  float* part = Li + LI_SZ;         // 13,107,200 floats (corr partials)
  // overlay after k_reduceP (part is dead then): LiT + Wrm + Wcm = 10,240,000
  float* LiT  = part;
  float* Wrm  = part + LI_SZ;
  float* Wcm  = Wrm + W_SZ;

  k_corrR_mfma<<<256, 640, 0, stream>>>(x, part);
  k_reduceR<<<R_SZ / 256, 256, 0, stream>>>(part, R);
  k_corrP_mfma<<<256, 640, 0, stream>>>(x, y, part);
  k_reduceP<<<P_SZ / 256, 256, 0, stream>>>(part, d, alpha, reg, P);
  k_buildQ<<<16 * 800, 256, 0, stream>>>(R, Q, alpha, reg);

  k_diag0<<<16, 256, 0, stream>>>(Q, Li, LiT);
  for (int t = 0; t < 9; ++t) {
    int nt = 9 - t;
    k_chol_step<<<16 * nt * (nt + 1) / 2, 256, 0, stream>>>(Q, Li, LiT, Wrm, Wcm, t);
  }

  k_solve<<<64, 640, 0, stream>>>(Li, LiT, Wrm, Wcm, P, out);
}